// Round 1
// 9012.567 us; speedup vs baseline: 1.0571x; 1.0571x over previous
//
#include <hip/hip_runtime.h>

#define NB 128
#define NN 512
#define NODES (NB * NN)
#define NLEVELS 64

typedef __attribute__((ext_vector_type(8))) short short8;
typedef __attribute__((ext_vector_type(4))) short short4v;
typedef __attribute__((ext_vector_type(4))) float f32x4;
typedef unsigned int u32;

__device__ __forceinline__ float bf2f(short s) {
    union { u32 u; float f; } v;
    v.u = ((u32)(unsigned short)s) << 16;
    return v.f;
}
__device__ __forceinline__ short f2bf(float f) {
    union { u32 u; float f; } v;
    v.f = f;
    u32 u = v.u + 0x7FFFu + ((v.u >> 16) & 1u);  // RNE
    return (short)(u >> 16);
}
// clamp that also sanitizes NaN (AMD v_min/v_max return the non-NaN operand)
__device__ __forceinline__ float fclamp(float x, float lo, float hi) {
    return fminf(fmaxf(x, lo), hi);
}
__device__ __forceinline__ float fsig(float x) {
    return __builtin_amdgcn_rcpf(1.f + __builtin_amdgcn_exp2f(-1.44269504f * x));
}
__device__ __forceinline__ float ftanh(float x) {
    return 1.f - 2.f * __builtin_amdgcn_rcpf(1.f + __builtin_amdgcn_exp2f(2.88539008f * x));
}
#define MFMA16(a, b, c) __builtin_amdgcn_mfma_f32_16x16x32_bf16((a), (b), (c), 0, 0, 0)

// ---------------------------------------------------------------------------
// fp32 -> bf16 (RNE) bulk converter, float4-vectorized grid-stride.
// ---------------------------------------------------------------------------
__global__ __launch_bounds__(256) void conv_kernel(
    const float* __restrict__ src, short* __restrict__ dst, int n4)
{
    int i = blockIdx.x * blockDim.x + threadIdx.x;
    const int stride = gridDim.x * blockDim.x;
    for (; i < n4; i += stride) {
        const f32x4 v = *(const f32x4*)(src + (size_t)i * 4);
        short4v o;
        o[0] = f2bf(v[0]); o[1] = f2bf(v[1]); o[2] = f2bf(v[2]); o[3] = f2bf(v[3]);
        *(short4v*)(dst + (size_t)i * 4) = o;
    }
}

// ---------------------------------------------------------------------------
// Setup, parallel version.
//   Z:   zero counts
//   S1:  per-tree depth via pointer doubling (9 iters cover depth<=512),
//        one block per tree, LDS-resident; LDS histogram -> global counts
//   S2:  exclusive scan over 520 level counts (LDS staged)
//   S3:  scatter nodes into level-sorted list (multi-block, cursor atomics)
// list entry: b<<18 | t<<9 | par
// ---------------------------------------------------------------------------
__global__ __launch_bounds__(256) void zero_kernel(int* __restrict__ counts)
{
    const int i = blockIdx.x * 256 + threadIdx.x;
    if (i < 520) counts[i] = 0;
}

__global__ __launch_bounds__(256) void depth_kernel(
    const int* __restrict__ conn,
    unsigned char* __restrict__ lvl_g,  // [NODES]
    int* __restrict__ counts)           // [520]
{
    __shared__ short anc[NN];
    __shared__ short dep[NN];
    __shared__ int hist[520];
    const int b = blockIdx.x;
    const int tid = threadIdx.x;

    for (int i = tid; i < 520; i += 256) hist[i] = 0;
    for (int i = tid; i < NN; i += 256) {
        anc[i] = (i == 0) ? (short)0 : (short)conn[b * NN + i];  // par < i
        dep[i] = (i == 0) ? (short)0 : (short)1;
    }
    __syncthreads();
    // binary lifting: after k iters, dep = #edges to ancestor at dist 2^k (root-clamped)
    for (int it = 0; it < 9; it++) {
        const int i0 = tid, i1 = tid + 256;
        const short a0 = anc[i0], d0 = dep[i0];
        const short a1 = anc[i1], d1 = dep[i1];
        const short da0 = dep[a0], aa0 = anc[a0];
        const short da1 = dep[a1], aa1 = anc[a1];
        __syncthreads();
        dep[i0] = (short)(d0 + da0); anc[i0] = aa0;
        dep[i1] = (short)(d1 + da1); anc[i1] = aa1;
        __syncthreads();
    }
    for (int i = tid; i < NN; i += 256) {
        const unsigned char d = (unsigned char)dep[i];
        lvl_g[b * NN + i] = d;
        atomicAdd(&hist[d], 1);
    }
    __syncthreads();
    for (int i = tid; i < 520; i += 256)
        if (hist[i]) atomicAdd(&counts[i], hist[i]);
}

__global__ __launch_bounds__(256) void scan_kernel(
    const int* __restrict__ counts,
    int* __restrict__ offs,
    int* __restrict__ cursor)
{
    __shared__ int c[520];
    __shared__ int o[520];
    const int tid = threadIdx.x;
    for (int i = tid; i < 520; i += 256) c[i] = counts[i];
    __syncthreads();
    if (tid == 0) {
        int acc = 0;
        for (int l = 0; l < 520; l++) { o[l] = acc; acc += c[l]; }
    }
    __syncthreads();
    for (int i = tid; i < 520; i += 256) {
        offs[i] = o[i];
        cursor[i] = o[i];
    }
}

__global__ __launch_bounds__(256) void scatter_kernel(
    const int* __restrict__ conn,
    const unsigned char* __restrict__ lvl_g,
    int* __restrict__ cursor,
    u32* __restrict__ list)
{
    int i = blockIdx.x * 256 + threadIdx.x;
    const int stride = gridDim.x * 256;
    for (; i < NODES; i += stride) {
        const int b = i >> 9, t = i & 511;
        const int l = lvl_g[i];
        const int par = (t == 0) ? 0 : conn[i];
        const int pos = atomicAdd(&cursor[l], 1);
        list[pos] = ((u32)b << 18) | ((u32)t << 9) | (u32)par;
    }
}

// ---------------------------------------------------------------------------
// One level of the tree wavefront. Each block grid-strides over 32-node tiles.
// All MFMA operands are pre-converted bf16 (embb, wlb, wrb, ulb, urb, h_bf).
// Phase A: pooled[m][g,p] = sum_r (emb.wl)*(h_par.wr)  -> LDS (fp32)
// Phase B: pre = emb.ul + h_par.ur + wo.pooled + bias (fp32 epilogue)
//          -> gates -> c (bf16 ws), h (fp32 d_out + bf16 ws)
// Pad rows (tile tail) read clamped row M-1 data but NEVER write.
// ---------------------------------------------------------------------------
__global__ __launch_bounds__(256) void level_kernel(
    const int lvl,
    const short* __restrict__ embb,
    const short* __restrict__ wlb,
    const short* __restrict__ wrb,
    const float* __restrict__ wo,
    const short* __restrict__ ulb,
    const short* __restrict__ urb,
    const float* __restrict__ bias,
    const int* __restrict__ offs,
    const u32* __restrict__ list,
    float* __restrict__ h_out,    // d_out fp32
    short* __restrict__ h_bf,     // ws bf16 (gather source for parent h)
    short* __restrict__ c_bf)     // ws bf16
{
    const int base = offs[lvl];
    const int M = offs[lvl + 1] - base;
    if (M <= 0) return;
    const int mt = (M + 31) >> 5;

    __shared__ float pooled_s[32 * 24];
    __shared__ u32 list_s[32];

    const int tid = threadIdx.x;
    const int lane = tid & 63;
    const int w = tid >> 6;    // wave 0..3
    const int q = lane >> 4;   // quad
    const int ln = lane & 15;

    for (int tile = blockIdx.x; tile < mt; tile += gridDim.x) {
        __syncthreads();
        if (tid < 32) {
            int mr = tile * 32 + tid;
            if (mr > M - 1) mr = M - 1;  // pad rows: duplicate row M-1 for reads only
            list_s[tid] = list[base + mr];
        }
        __syncthreads();

        // ---------------- phase A: bilinear pooled ----------------
        if (lvl > 0) {  // level 0: ph==0 -> pooled==0 (phase B skips it)
            const short* arE[2];
            const short* arH[2];
#pragma unroll
            for (int ms = 0; ms < 2; ms++) {
                const u32 pk = list_s[ms * 16 + ln];
                const int bb = pk >> 18, tt = (pk >> 9) & 511, pp = pk & 511;
                arE[ms] = embb + ((size_t)((bb << 9) | tt) << 9);
                arH[ms] = h_bf + ((size_t)((bb << 9) | pp) << 9);
            }
            for (int cb = w; cb < 24; cb += 4) {
                const int g = cb >> 3, p = cb & 7;
                const short* wL = wlb + ((size_t)(((g << 3) | p) << 6) << 9);
                const short* wR = wrb + ((size_t)(((g << 3) | p) << 6) << 9);
                f32x4 aL[2][4], aR[2][4];
#pragma unroll
                for (int ms = 0; ms < 2; ms++)
#pragma unroll
                    for (int nt = 0; nt < 4; nt++) {
                        aL[ms][nt] = {0.f, 0.f, 0.f, 0.f};
                        aR[ms][nt] = {0.f, 0.f, 0.f, 0.f};
                    }
                for (int ks = 0; ks < 16; ks++) {
                    const int k0 = (ks << 5) + (q << 3);
                    const short8 aE0 = *(const short8*)(arE[0] + k0);
                    const short8 aE1 = *(const short8*)(arE[1] + k0);
                    const short8 aH0 = *(const short8*)(arH[0] + k0);
                    const short8 aH1 = *(const short8*)(arH[1] + k0);
#pragma unroll
                    for (int nt = 0; nt < 4; nt++) {
                        const short8 bL = *(const short8*)(wL + ((nt << 4) + ln) * 512 + k0);
                        const short8 bR = *(const short8*)(wR + ((nt << 4) + ln) * 512 + k0);
                        aL[0][nt] = MFMA16(aE0, bL, aL[0][nt]);
                        aL[1][nt] = MFMA16(aE1, bL, aL[1][nt]);
                        aR[0][nt] = MFMA16(aH0, bR, aR[0][nt]);
                        aR[1][nt] = MFMA16(aH1, bR, aR[1][nt]);
                    }
                }
#pragma unroll
                for (int ms = 0; ms < 2; ms++) {
#pragma unroll
                    for (int reg = 0; reg < 4; reg++) {
                        float v = 0.f;
#pragma unroll
                        for (int nt = 0; nt < 4; nt++)
                            v += aL[ms][nt][reg] * aR[ms][nt][reg];
                        v += __shfl_xor(v, 1, 64);
                        v += __shfl_xor(v, 2, 64);
                        v += __shfl_xor(v, 4, 64);
                        v += __shfl_xor(v, 8, 64);
                        if (ln == 0)
                            pooled_s[(ms * 16 + (q << 2) + reg) * 24 + cb] = v;
                    }
                }
            }
        }
        __syncthreads();

        // ---------------- phase B: linear terms + gates + state update ----------------
        {
            const short* arE[2];
            const short* arH[2];
#pragma unroll
            for (int ms = 0; ms < 2; ms++) {
                const u32 pk = list_s[ms * 16 + ln];
                const int bb = pk >> 18, tt = (pk >> 9) & 511, pp = pk & 511;
                arE[ms] = embb + ((size_t)((bb << 9) | tt) << 9);
                arH[ms] = h_bf + ((size_t)((bb << 9) | pp) << 9);
            }
            for (int hb = w * 2; hb < w * 2 + 2; hb++) {
                f32x4 acc[3][2][4];
#pragma unroll
                for (int g = 0; g < 3; g++)
#pragma unroll
                    for (int ms = 0; ms < 2; ms++)
#pragma unroll
                        for (int nt = 0; nt < 4; nt++)
                            acc[g][ms][nt] = {0.f, 0.f, 0.f, 0.f};
                // pass 1: emb x ul
                for (int ks = 0; ks < 16; ks++) {
                    const int k0 = (ks << 5) + (q << 3);
                    const short8 aE0 = *(const short8*)(arE[0] + k0);
                    const short8 aE1 = *(const short8*)(arE[1] + k0);
#pragma unroll
                    for (int g = 0; g < 3; g++)
#pragma unroll
                        for (int nt = 0; nt < 4; nt++) {
                            const int col = (g << 9) + (hb << 6) + (nt << 4) + ln;
                            const short8 bv = *(const short8*)(ulb + ((size_t)col << 9) + k0);
                            acc[g][0][nt] = MFMA16(aE0, bv, acc[g][0][nt]);
                            acc[g][1][nt] = MFMA16(aE1, bv, acc[g][1][nt]);
                        }
                }
                // pass 2: h_par x ur (skip at root level: ph==0)
                if (lvl > 0) {
                    for (int ks = 0; ks < 16; ks++) {
                        const int k0 = (ks << 5) + (q << 3);
                        const short8 aH0 = *(const short8*)(arH[0] + k0);
                        const short8 aH1 = *(const short8*)(arH[1] + k0);
#pragma unroll
                        for (int g = 0; g < 3; g++)
#pragma unroll
                            for (int nt = 0; nt < 4; nt++) {
                                const int col = (g << 9) + (hb << 6) + (nt << 4) + ln;
                                const short8 bv = *(const short8*)(urb + ((size_t)col << 9) + k0);
                                acc[g][0][nt] = MFMA16(aH0, bv, acc[g][0][nt]);
                                acc[g][1][nt] = MFMA16(aH1, bv, acc[g][1][nt]);
                            }
                    }
                }
                // epilogue (fp32) — pad rows (tile*32+lr >= M) write nothing
#pragma unroll
                for (int ms = 0; ms < 2; ms++) {
#pragma unroll
                    for (int nt = 0; nt < 4; nt++) {
                        const int h = (hb << 6) + (nt << 4) + ln;
#pragma unroll
                        for (int reg = 0; reg < 4; reg++) {
                            const int lr = ms * 16 + (q << 2) + reg;  // local row
                            if (tile * 32 + lr >= M) continue;        // pad: no write
                            float pre[3];
#pragma unroll
                            for (int g = 0; g < 3; g++) {
                                float v = acc[g][ms][nt][reg] + bias[(g << 9) + h];
                                if (lvl > 0) {
                                    const float* pp = pooled_s + lr * 24 + (g << 3);
                                    const float* wop = wo + (((g << 9) + h) << 3);
                                    float sdot = 0.f;
#pragma unroll
                                    for (int p2 = 0; p2 < 8; p2++)
                                        sdot += pp[p2] * wop[p2];
                                    v += sdot;
                                }
                                // clamp + NaN-sanitize (min/max drop NaN on AMD)
                                pre[g] = fclamp(v, -30.f, 30.f);
                            }
                            const float fg = fsig(pre[0]);
                            const float og = fsig(pre[1]);
                            const float zg = ftanh(pre[2]);
                            const u32 pk = list_s[lr];
                            const int bb = pk >> 18, tt = (pk >> 9) & 511, pp2 = pk & 511;
                            float pc = 0.f;
                            if (lvl > 0) {
                                pc = bf2f(c_bf[((size_t)((bb << 9) | pp2) << 9) + h]);
                                pc = fclamp(pc, -1.f, 1.f);  // |c|<=1 by induction
                            }
                            const float cc = pc * fg + (1.f - fg) * zg;
                            const float hh = og * ftanh(cc);
                            const size_t oi = ((size_t)((bb << 9) | tt) << 9) + h;
                            c_bf[oi] = f2bf(cc);
                            h_bf[oi] = f2bf(hh);
                            h_out[oi] = hh;
                        }
                    }
                }
            }
        }
    }
}

extern "C" void kernel_launch(void* const* d_in, const int* in_sizes, int n_in,
                              void* d_out, int out_size, void* d_ws, size_t ws_size,
                              hipStream_t stream) {
    const float* emb  = (const float*)d_in[0];  // (B,N,IN) fp32
    const int*   conn = (const int*)d_in[1];    // (B,N) int32
    // d_in[2] node_mask: all ones, unused
    const float* wl   = (const float*)d_in[3];  // (3,8,64,512) fp32
    const float* wr   = (const float*)d_in[4];  // (3,8,64,512) fp32
    const float* wo   = (const float*)d_in[5];  // (3,512,8)    fp32
    const float* ul   = (const float*)d_in[6];  // (3,512,512)  fp32
    const float* ur   = (const float*)d_in[7];  // (3,512,512)  fp32
    const float* bias = (const float*)d_in[8];  // (3,512)      fp32

    char* ws = (char*)d_ws;
    int* offs   = (int*)ws;          // 520
    int* counts = offs + 520;        // 520
    int* cursor = counts + 520;      // 520
    unsigned char* lvl_g = (unsigned char*)(ws + 8192);   // 64 KiB
    u32* list = (u32*)(ws + 8192 + 65536);                // 256 KiB
    // bf16 staging (byte offsets from ws base):
    short* wlb = (short*)(ws + 335872);                   // 786432 el
    short* wrb = wlb + 786432;
    short* ulb = wrb + 786432;
    short* urb = ulb + 786432;                            // ends ~6.6 MB
    short* embb = (short*)(ws + (8u << 20));              // 64 MiB  (33.5M el)
    short* h_bf = (short*)(ws + (8u << 20) + 67108864u);
    short* c_bf = (short*)(ws + (8u << 20) + 134217728u); // ends at 200 MiB

    float* h_out = (float*)d_out;

    // fp32 -> bf16 staging
    conv_kernel<<<dim3(2048), dim3(256), 0, stream>>>(emb, embb, NODES * 512 / 4);
    conv_kernel<<<dim3(256), dim3(256), 0, stream>>>(wl, wlb, 786432 / 4);
    conv_kernel<<<dim3(256), dim3(256), 0, stream>>>(wr, wrb, 786432 / 4);
    conv_kernel<<<dim3(256), dim3(256), 0, stream>>>(ul, ulb, 786432 / 4);
    conv_kernel<<<dim3(256), dim3(256), 0, stream>>>(ur, urb, 786432 / 4);

    // parallel setup: zero -> depth(pointer doubling)+hist -> scan -> scatter
    zero_kernel<<<dim3(3), dim3(256), 0, stream>>>(counts);
    depth_kernel<<<dim3(NB), dim3(256), 0, stream>>>(conn, lvl_g, counts);
    scan_kernel<<<dim3(1), dim3(256), 0, stream>>>(counts, offs, cursor);
    scatter_kernel<<<dim3(256), dim3(256), 0, stream>>>(conn, lvl_g, cursor, list);

    for (int l = 0; l < NLEVELS; l++) {
        level_kernel<<<dim3(512), dim3(256), 0, stream>>>(
            l, embb, wlb, wrb, wo, ulb, urb, bias, offs, list, h_out, h_bf, c_bf);
    }
}

// Round 2
// 4413.427 us; speedup vs baseline: 2.1586x; 2.0421x over previous
//
#include <hip/hip_runtime.h>

#define NB 128
#define NN 512
#define NODES (NB * NN)
#define NLEVELS 64

typedef __attribute__((ext_vector_type(8))) short short8;
typedef __attribute__((ext_vector_type(4))) short short4v;
typedef __attribute__((ext_vector_type(4))) float f32x4;
typedef unsigned int u32;

__device__ __forceinline__ float bf2f(short s) {
    union { u32 u; float f; } v;
    v.u = ((u32)(unsigned short)s) << 16;
    return v.f;
}
__device__ __forceinline__ short f2bf(float f) {
    union { u32 u; float f; } v;
    v.f = f;
    u32 u = v.u + 0x7FFFu + ((v.u >> 16) & 1u);  // RNE
    return (short)(u >> 16);
}
// clamp that also sanitizes NaN (AMD v_min/v_max return the non-NaN operand)
__device__ __forceinline__ float fclamp(float x, float lo, float hi) {
    return fminf(fmaxf(x, lo), hi);
}
__device__ __forceinline__ float fsig(float x) {
    return __builtin_amdgcn_rcpf(1.f + __builtin_amdgcn_exp2f(-1.44269504f * x));
}
__device__ __forceinline__ float ftanh(float x) {
    return 1.f - 2.f * __builtin_amdgcn_rcpf(1.f + __builtin_amdgcn_exp2f(2.88539008f * x));
}
#define MFMA16(a, b, c) __builtin_amdgcn_mfma_f32_16x16x32_bf16((a), (b), (c), 0, 0, 0)
// LDS XOR swizzle for [row][512 bf16] tiles read 16B/lane at row stride 1KB:
// spreads rows 0..7 across 8 distinct 16B slots -> ~2-way (free) instead of 16-way.
#define SWZ(b) ((b) ^ (((b) >> 6) & 0x70))

// ---------------------------------------------------------------------------
// fp32 -> bf16 (RNE) bulk converter, float4-vectorized grid-stride.
// ---------------------------------------------------------------------------
__global__ __launch_bounds__(256) void conv_kernel(
    const float* __restrict__ src, short* __restrict__ dst, int n4)
{
    int i = blockIdx.x * blockDim.x + threadIdx.x;
    const int stride = gridDim.x * blockDim.x;
    for (; i < n4; i += stride) {
        const f32x4 v = *(const f32x4*)(src + (size_t)i * 4);
        short4v o;
        o[0] = f2bf(v[0]); o[1] = f2bf(v[1]); o[2] = f2bf(v[2]); o[3] = f2bf(v[3]);
        *(short4v*)(dst + (size_t)i * 4) = o;
    }
}

// ---------------------------------------------------------------------------
// Setup (parallel): zero -> depth (pointer doubling, 1 block/tree) -> scan ->
// scatter into level-sorted list. list entry: b<<18 | t<<9 | par
// ---------------------------------------------------------------------------
__global__ __launch_bounds__(256) void zero_kernel(int* __restrict__ counts)
{
    const int i = blockIdx.x * 256 + threadIdx.x;
    if (i < 520) counts[i] = 0;
}

__global__ __launch_bounds__(256) void depth_kernel(
    const int* __restrict__ conn,
    unsigned char* __restrict__ lvl_g,  // [NODES]
    int* __restrict__ counts)           // [520]
{
    __shared__ short anc[NN];
    __shared__ short dep[NN];
    __shared__ int hist[520];
    const int b = blockIdx.x;
    const int tid = threadIdx.x;

    for (int i = tid; i < 520; i += 256) hist[i] = 0;
    for (int i = tid; i < NN; i += 256) {
        anc[i] = (i == 0) ? (short)0 : (short)conn[b * NN + i];  // par < i
        dep[i] = (i == 0) ? (short)0 : (short)1;
    }
    __syncthreads();
    for (int it = 0; it < 9; it++) {
        const int i0 = tid, i1 = tid + 256;
        const short a0 = anc[i0], d0 = dep[i0];
        const short a1 = anc[i1], d1 = dep[i1];
        const short da0 = dep[a0], aa0 = anc[a0];
        const short da1 = dep[a1], aa1 = anc[a1];
        __syncthreads();
        dep[i0] = (short)(d0 + da0); anc[i0] = aa0;
        dep[i1] = (short)(d1 + da1); anc[i1] = aa1;
        __syncthreads();
    }
    for (int i = tid; i < NN; i += 256) {
        const unsigned char d = (unsigned char)dep[i];
        lvl_g[b * NN + i] = d;
        atomicAdd(&hist[d], 1);
    }
    __syncthreads();
    for (int i = tid; i < 520; i += 256)
        if (hist[i]) atomicAdd(&counts[i], hist[i]);
}

__global__ __launch_bounds__(256) void scan_kernel(
    const int* __restrict__ counts,
    int* __restrict__ offs,
    int* __restrict__ cursor)
{
    __shared__ int c[520];
    __shared__ int o[520];
    const int tid = threadIdx.x;
    for (int i = tid; i < 520; i += 256) c[i] = counts[i];
    __syncthreads();
    if (tid == 0) {
        int acc = 0;
        for (int l = 0; l < 520; l++) { o[l] = acc; acc += c[l]; }
    }
    __syncthreads();
    for (int i = tid; i < 520; i += 256) {
        offs[i] = o[i];
        cursor[i] = o[i];
    }
}

__global__ __launch_bounds__(256) void scatter_kernel(
    const int* __restrict__ conn,
    const unsigned char* __restrict__ lvl_g,
    int* __restrict__ cursor,
    u32* __restrict__ list)
{
    int i = blockIdx.x * 256 + threadIdx.x;
    const int stride = gridDim.x * 256;
    for (; i < NODES; i += stride) {
        const int b = i >> 9, t = i & 511;
        const int l = lvl_g[i];
        const int par = (t == 0) ? 0 : conn[i];
        const int pos = atomicAdd(&cursor[l], 1);
        list[pos] = ((u32)b << 18) | ((u32)t << 9) | (u32)par;
    }
}

// ---------------------------------------------------------------------------
// pool_kernel: bilinear pooled partials for one level.
// Slice = (gp, r-half): 48 slices; slice = bid % 48 (=> XCD-resident weights).
// Each block stages its 64 KiB (wl,wr 32-row halves) slice in swizzled LDS,
// then grid-strides 16-row wave-tiles. Output: pooled2[mr*48 + gp*2 + rh]
// = sum over the 32 r of this half of (emb.wl_r)*(h_par.wr_r). lin sums halves.
// Only launched for lvl > 0.
// ---------------------------------------------------------------------------
__global__ __launch_bounds__(256) void pool_kernel(
    const int lvl,
    const short* __restrict__ embb,
    const short* __restrict__ wlb,
    const short* __restrict__ wrb,
    const short* __restrict__ h_bf,
    const int* __restrict__ offs,
    const u32* __restrict__ list,
    float* __restrict__ pooled2)
{
    const int base = offs[lvl];
    const int M = offs[lvl + 1] - base;
    if (M <= 0) return;
    const int T = (M + 15) >> 4;  // 16-row wave tiles

    const int s = blockIdx.x % 48;        // slice id: gp = s>>1, rhalf = s&1
    const int rb = blockIdx.x / 48;
    const int nb = gridDim.x / 48;        // blocks per slice
    if (rb * 4 >= T) return;              // no tiles for any wave of this block

    const int tid = threadIdx.x;
    const int lane = tid & 63;
    const int w = tid >> 6;
    const int q = lane >> 4;
    const int ln = lane & 15;

    __shared__ short wsm[2 * 32 * 512];   // 64 KiB: wl half | wr half (swizzled)
    {
        const int gp = s >> 1, rh = s & 1;
        const short* gwl = wlb + (((size_t)gp * 64 + rh * 32) << 9);
        const short* gwr = wrb + (((size_t)gp * 64 + rh * 32) << 9);
        for (int i = tid; i < 2048; i += 256) {
            const int byte = i << 4;
            *(short8*)((char*)wsm + SWZ(byte)) = *(const short8*)((const char*)gwl + byte);
            *(short8*)((char*)wsm + 32768 + SWZ(byte)) = *(const short8*)((const char*)gwr + byte);
        }
    }
    __syncthreads();

    for (int tile = rb * 4 + w; tile < T; tile += nb * 4) {
        const int mr0 = tile << 4;
        const int ar = mr0 + ln;
        const u32 pk = list[base + (ar < M ? ar : M - 1)];
        const int bb = pk >> 18, tt = (pk >> 9) & 511, pp = pk & 511;
        const short* aE = embb + ((size_t)((bb << 9) | tt) << 9);
        const short* aH = h_bf + ((size_t)((bb << 9) | pp) << 9);

        f32x4 aL[2], aR[2];
#pragma unroll
        for (int nt = 0; nt < 2; nt++) {
            aL[nt] = {0.f, 0.f, 0.f, 0.f};
            aR[nt] = {0.f, 0.f, 0.f, 0.f};
        }
        for (int ks = 0; ks < 16; ks++) {
            const int k0 = (ks << 5) + (q << 3);
            const short8 e = *(const short8*)(aE + k0);
            const short8 h = *(const short8*)(aH + k0);
#pragma unroll
            for (int nt = 0; nt < 2; nt++) {
                const int byte = (((nt << 4) + ln) << 10) + (k0 << 1);
                const short8 bL = *(const short8*)((const char*)wsm + SWZ(byte));
                const short8 bR = *(const short8*)((const char*)wsm + 32768 + SWZ(byte));
                aL[nt] = MFMA16(e, bL, aL[nt]);
                aR[nt] = MFMA16(h, bR, aR[nt]);
            }
        }
        // product over matching r, reduce over the 32 r of this half
#pragma unroll
        for (int reg = 0; reg < 4; reg++) {
            float v = aL[0][reg] * aR[0][reg] + aL[1][reg] * aR[1][reg];
            v += __shfl_xor(v, 1, 64);
            v += __shfl_xor(v, 2, 64);
            v += __shfl_xor(v, 4, 64);
            v += __shfl_xor(v, 8, 64);
            if (ln == 0) {
                const int mr = mr0 + (q << 2) + reg;
                if (mr < M) pooled2[(size_t)mr * 48 + s] = v;
            }
        }
    }
}

// ---------------------------------------------------------------------------
// lin_kernel: linear terms + epilogue for one level.
// Slice = 64 h-cols (all 3 gates): slc = bid & 7 => ul/ur slice (384 KB)
// stays XCD-L2-resident across tiles AND across level launches.
// 4 waves share a 32-row tile; wave w owns h-cols slc*64 + w*16 + ln.
// acc[3 gates][2 row-halves] = 24 VGPR -> compiler can pipeline loads.
// ---------------------------------------------------------------------------
__global__ __launch_bounds__(256) void lin_kernel(
    const int lvl,
    const short* __restrict__ embb,
    const short* __restrict__ ulb,
    const short* __restrict__ urb,
    const float* __restrict__ wo,
    const float* __restrict__ bias,
    const int* __restrict__ offs,
    const u32* __restrict__ list,
    const float* __restrict__ pooled2,
    float* __restrict__ h_out,    // d_out fp32
    short* __restrict__ h_bf,     // ws bf16 (gather source for parent h)
    short* __restrict__ c_bf)     // ws bf16
{
    const int base = offs[lvl];
    const int M = offs[lvl + 1] - base;
    if (M <= 0) return;
    const int T = (M + 31) >> 5;  // 32-row block tiles

    const int slc = blockIdx.x & 7;
    const int rb = blockIdx.x >> 3;
    const int nb = gridDim.x >> 3;

    const int tid = threadIdx.x;
    const int lane = tid & 63;
    const int w = tid >> 6;
    const int q = lane >> 4;
    const int ln = lane & 15;
    const int h = (slc << 6) + (w << 4) + ln;  // this lane's output column

    const float b0 = bias[h], b1 = bias[512 + h], b2 = bias[1024 + h];
    const float* wo0 = wo + ((size_t)h << 3);
    const float* wo1 = wo + ((size_t)(512 + h) << 3);
    const float* wo2 = wo + ((size_t)(1024 + h) << 3);

    for (int tile = rb; tile < T; tile += nb) {
        const int mr0 = tile << 5;
        const short *aEp[2], *aHp[2];
#pragma unroll
        for (int ms = 0; ms < 2; ms++) {
            const int ar = mr0 + (ms << 4) + ln;
            const u32 pk = list[base + (ar < M ? ar : M - 1)];
            const int bb = pk >> 18, tt = (pk >> 9) & 511, pp = pk & 511;
            aEp[ms] = embb + ((size_t)((bb << 9) | tt) << 9);
            aHp[ms] = h_bf + ((size_t)((bb << 9) | pp) << 9);
        }

        f32x4 acc[3][2];
#pragma unroll
        for (int g = 0; g < 3; g++)
#pragma unroll
            for (int ms = 0; ms < 2; ms++)
                acc[g][ms] = {0.f, 0.f, 0.f, 0.f};

        for (int ks = 0; ks < 16; ks++) {
            const int k0 = (ks << 5) + (q << 3);
            const short8 e0 = *(const short8*)(aEp[0] + k0);
            const short8 e1 = *(const short8*)(aEp[1] + k0);
#pragma unroll
            for (int g = 0; g < 3; g++) {
                const short8 bu = *(const short8*)(ulb + ((size_t)((g << 9) + h) << 9) + k0);
                acc[g][0] = MFMA16(e0, bu, acc[g][0]);
                acc[g][1] = MFMA16(e1, bu, acc[g][1]);
            }
            if (lvl > 0) {
                const short8 h0 = *(const short8*)(aHp[0] + k0);
                const short8 h1 = *(const short8*)(aHp[1] + k0);
#pragma unroll
                for (int g = 0; g < 3; g++) {
                    const short8 br = *(const short8*)(urb + ((size_t)((g << 9) + h) << 9) + k0);
                    acc[g][0] = MFMA16(h0, br, acc[g][0]);
                    acc[g][1] = MFMA16(h1, br, acc[g][1]);
                }
            }
        }

        // epilogue (fp32) — pad rows (mr >= M) write nothing
#pragma unroll
        for (int ms = 0; ms < 2; ms++) {
#pragma unroll
            for (int reg = 0; reg < 4; reg++) {
                const int mr = mr0 + (ms << 4) + (q << 2) + reg;
                if (mr >= M) continue;
                const u32 pk = list[base + mr];
                const int bb = pk >> 18, tt = (pk >> 9) & 511, pp2 = pk & 511;
                float v0 = acc[0][ms][reg] + b0;
                float v1 = acc[1][ms][reg] + b1;
                float v2 = acc[2][ms][reg] + b2;
                if (lvl > 0) {
                    const float* pr = pooled2 + (size_t)mr * 48;
                    float s0 = 0.f, s1 = 0.f, s2 = 0.f;
#pragma unroll
                    for (int p2 = 0; p2 < 8; p2++) {
                        s0 += (pr[p2 * 2] + pr[p2 * 2 + 1]) * wo0[p2];
                        s1 += (pr[16 + p2 * 2] + pr[16 + p2 * 2 + 1]) * wo1[p2];
                        s2 += (pr[32 + p2 * 2] + pr[32 + p2 * 2 + 1]) * wo2[p2];
                    }
                    v0 += s0; v1 += s1; v2 += s2;
                }
                // clamp + NaN-sanitize (min/max drop NaN on AMD)
                const float fg = fsig(fclamp(v0, -30.f, 30.f));
                const float og = fsig(fclamp(v1, -30.f, 30.f));
                const float zg = ftanh(fclamp(v2, -30.f, 30.f));
                float pc = 0.f;
                if (lvl > 0) {
                    pc = bf2f(c_bf[((size_t)((bb << 9) | pp2) << 9) + h]);
                    pc = fclamp(pc, -1.f, 1.f);  // |c|<=1 by induction
                }
                const float cc = pc * fg + (1.f - fg) * zg;
                const float hh = og * ftanh(cc);
                const size_t oi = ((size_t)((bb << 9) | tt) << 9) + h;
                c_bf[oi] = f2bf(cc);
                h_bf[oi] = f2bf(hh);
                h_out[oi] = hh;
            }
        }
    }
}

extern "C" void kernel_launch(void* const* d_in, const int* in_sizes, int n_in,
                              void* d_out, int out_size, void* d_ws, size_t ws_size,
                              hipStream_t stream) {
    const float* emb  = (const float*)d_in[0];  // (B,N,IN) fp32
    const int*   conn = (const int*)d_in[1];    // (B,N) int32
    // d_in[2] node_mask: all ones, unused
    const float* wl   = (const float*)d_in[3];  // (3,8,64,512) fp32
    const float* wr   = (const float*)d_in[4];  // (3,8,64,512) fp32
    const float* wo   = (const float*)d_in[5];  // (3,512,8)    fp32
    const float* ul   = (const float*)d_in[6];  // (3,512,512)  fp32
    const float* ur   = (const float*)d_in[7];  // (3,512,512)  fp32
    const float* bias = (const float*)d_in[8];  // (3,512)      fp32

    char* ws = (char*)d_ws;
    int* offs   = (int*)ws;          // 520
    int* counts = offs + 520;        // 520
    int* cursor = counts + 520;      // 520
    unsigned char* lvl_g = (unsigned char*)(ws + 8192);   // 64 KiB
    u32* list = (u32*)(ws + 8192 + 65536);                // 256 KiB
    // bf16 staging (byte offsets from ws base):
    short* wlb = (short*)(ws + 335872);                   // 786432 el
    short* wrb = wlb + 786432;
    short* ulb = wrb + 786432;
    short* urb = ulb + 786432;                            // ends ~6.6 MB
    short* embb = (short*)(ws + (8u << 20));              // 64 MiB
    short* h_bf = (short*)(ws + (8u << 20) + 67108864u);
    short* c_bf = (short*)(ws + (8u << 20) + 134217728u); // ends at 200 MiB
    float* pooled2 = (float*)(ws + 209715200ull);         // 12.6 MB (needs ws >= 213 MiB)

    float* h_out = (float*)d_out;

    // fp32 -> bf16 staging
    conv_kernel<<<dim3(2048), dim3(256), 0, stream>>>(emb, embb, NODES * 512 / 4);
    conv_kernel<<<dim3(256), dim3(256), 0, stream>>>(wl, wlb, 786432 / 4);
    conv_kernel<<<dim3(256), dim3(256), 0, stream>>>(wr, wrb, 786432 / 4);
    conv_kernel<<<dim3(256), dim3(256), 0, stream>>>(ul, ulb, 786432 / 4);
    conv_kernel<<<dim3(256), dim3(256), 0, stream>>>(ur, urb, 786432 / 4);

    // parallel setup: zero -> depth(pointer doubling)+hist -> scan -> scatter
    zero_kernel<<<dim3(3), dim3(256), 0, stream>>>(counts);
    depth_kernel<<<dim3(NB), dim3(256), 0, stream>>>(conn, lvl_g, counts);
    scan_kernel<<<dim3(1), dim3(256), 0, stream>>>(counts, offs, cursor);
    scatter_kernel<<<dim3(256), dim3(256), 0, stream>>>(conn, lvl_g, cursor, list);

    for (int l = 0; l < NLEVELS; l++) {
        if (l > 0)
            pool_kernel<<<dim3(480), dim3(256), 0, stream>>>(
                l, embb, wlb, wrb, h_bf, offs, list, pooled2);
        lin_kernel<<<dim3(512), dim3(256), 0, stream>>>(
            l, embb, ulb, urb, wo, bias, offs, list, pooled2, h_out, h_bf, c_bf);
    }
}

// Round 3
// 4230.202 us; speedup vs baseline: 2.2521x; 1.0433x over previous
//
#include <hip/hip_runtime.h>

#define NB 128
#define NN 512
#define NODES (NB * NN)
#define NLEVELS 64

typedef __attribute__((ext_vector_type(8))) short short8;
typedef __attribute__((ext_vector_type(4))) short short4v;
typedef __attribute__((ext_vector_type(4))) float f32x4;
typedef unsigned int u32;

__device__ __forceinline__ float bf2f(short s) {
    union { u32 u; float f; } v;
    v.u = ((u32)(unsigned short)s) << 16;
    return v.f;
}
__device__ __forceinline__ short f2bf(float f) {
    union { u32 u; float f; } v;
    v.f = f;
    u32 u = v.u + 0x7FFFu + ((v.u >> 16) & 1u);  // RNE
    return (short)(u >> 16);
}
// clamp that also sanitizes NaN (AMD v_min/v_max return the non-NaN operand)
__device__ __forceinline__ float fclamp(float x, float lo, float hi) {
    return fminf(fmaxf(x, lo), hi);
}
__device__ __forceinline__ float fsig(float x) {
    return __builtin_amdgcn_rcpf(1.f + __builtin_amdgcn_exp2f(-1.44269504f * x));
}
__device__ __forceinline__ float ftanh(float x) {
    return 1.f - 2.f * __builtin_amdgcn_rcpf(1.f + __builtin_amdgcn_exp2f(2.88539008f * x));
}
#define MFMA16(a, b, c) __builtin_amdgcn_mfma_f32_16x16x32_bf16((a), (b), (c), 0, 0, 0)
// LDS XOR swizzle for [row][512 bf16] tiles read 16B/lane at row stride 1KB:
#define SWZ(b) ((b) ^ (((b) >> 6) & 0x70))

// async global->LDS 16B (per-lane global source, wave-uniform LDS dest + lane*16)
__device__ __forceinline__ void gl16(const void* g, void* l) {
    __builtin_amdgcn_global_load_lds(
        (const __attribute__((address_space(1))) unsigned int*)g,
        (__attribute__((address_space(3))) unsigned int*)l,
        16, 0, 0);
}

// ---------------------------------------------------------------------------
// fp32 -> bf16 (RNE) bulk converter, float4-vectorized grid-stride.
// ---------------------------------------------------------------------------
__global__ __launch_bounds__(256) void conv_kernel(
    const float* __restrict__ src, short* __restrict__ dst, int n4)
{
    int i = blockIdx.x * blockDim.x + threadIdx.x;
    const int stride = gridDim.x * blockDim.x;
    for (; i < n4; i += stride) {
        const f32x4 v = *(const f32x4*)(src + (size_t)i * 4);
        short4v o;
        o[0] = f2bf(v[0]); o[1] = f2bf(v[1]); o[2] = f2bf(v[2]); o[3] = f2bf(v[3]);
        *(short4v*)(dst + (size_t)i * 4) = o;
    }
}

// ---------------------------------------------------------------------------
// Setup (parallel): zero -> depth (pointer doubling, 1 block/tree) -> scan ->
// scatter into level-sorted list. list entry: b<<18 | t<<9 | par
// ---------------------------------------------------------------------------
__global__ __launch_bounds__(256) void zero_kernel(int* __restrict__ counts)
{
    const int i = blockIdx.x * 256 + threadIdx.x;
    if (i < 520) counts[i] = 0;
}

__global__ __launch_bounds__(256) void depth_kernel(
    const int* __restrict__ conn,
    unsigned char* __restrict__ lvl_g,  // [NODES]
    int* __restrict__ counts)           // [520]
{
    __shared__ short anc[NN];
    __shared__ short dep[NN];
    __shared__ int hist[520];
    const int b = blockIdx.x;
    const int tid = threadIdx.x;

    for (int i = tid; i < 520; i += 256) hist[i] = 0;
    for (int i = tid; i < NN; i += 256) {
        anc[i] = (i == 0) ? (short)0 : (short)conn[b * NN + i];  // par < i
        dep[i] = (i == 0) ? (short)0 : (short)1;
    }
    __syncthreads();
    for (int it = 0; it < 9; it++) {
        const int i0 = tid, i1 = tid + 256;
        const short a0 = anc[i0], d0 = dep[i0];
        const short a1 = anc[i1], d1 = dep[i1];
        const short da0 = dep[a0], aa0 = anc[a0];
        const short da1 = dep[a1], aa1 = anc[a1];
        __syncthreads();
        dep[i0] = (short)(d0 + da0); anc[i0] = aa0;
        dep[i1] = (short)(d1 + da1); anc[i1] = aa1;
        __syncthreads();
    }
    for (int i = tid; i < NN; i += 256) {
        const unsigned char d = (unsigned char)dep[i];
        lvl_g[b * NN + i] = d;
        atomicAdd(&hist[d], 1);
    }
    __syncthreads();
    for (int i = tid; i < 520; i += 256)
        if (hist[i]) atomicAdd(&counts[i], hist[i]);
}

__global__ __launch_bounds__(256) void scan_kernel(
    const int* __restrict__ counts,
    int* __restrict__ offs,
    int* __restrict__ cursor)
{
    __shared__ int c[520];
    __shared__ int o[520];
    const int tid = threadIdx.x;
    for (int i = tid; i < 520; i += 256) c[i] = counts[i];
    __syncthreads();
    if (tid == 0) {
        int acc = 0;
        for (int l = 0; l < 520; l++) { o[l] = acc; acc += c[l]; }
    }
    __syncthreads();
    for (int i = tid; i < 520; i += 256) {
        offs[i] = o[i];
        cursor[i] = o[i];
    }
}

__global__ __launch_bounds__(256) void scatter_kernel(
    const int* __restrict__ conn,
    const unsigned char* __restrict__ lvl_g,
    int* __restrict__ cursor,
    u32* __restrict__ list)
{
    int i = blockIdx.x * 256 + threadIdx.x;
    const int stride = gridDim.x * 256;
    for (; i < NODES; i += stride) {
        const int b = i >> 9, t = i & 511;
        const int l = lvl_g[i];
        const int par = (t == 0) ? 0 : conn[i];
        const int pos = atomicAdd(&cursor[l], 1);
        list[pos] = ((u32)b << 18) | ((u32)t << 9) | (u32)par;
    }
}

// ---------------------------------------------------------------------------
// pool_kernel: bilinear pooled partials for one level (unchanged this round).
// Slice = (gp, r-half): 48 slices; slice = bid % 48 (=> XCD-resident weights).
// Output: pooled2[mr*48 + gp*2 + rh]. Only launched for lvl > 0.
// ---------------------------------------------------------------------------
__global__ __launch_bounds__(256) void pool_kernel(
    const int lvl,
    const short* __restrict__ embb,
    const short* __restrict__ wlb,
    const short* __restrict__ wrb,
    const short* __restrict__ h_bf,
    const int* __restrict__ offs,
    const u32* __restrict__ list,
    float* __restrict__ pooled2)
{
    const int base = offs[lvl];
    const int M = offs[lvl + 1] - base;
    if (M <= 0) return;
    const int T = (M + 15) >> 4;  // 16-row wave tiles

    const int s = blockIdx.x % 48;        // slice id: gp = s>>1, rhalf = s&1
    const int rb = blockIdx.x / 48;
    const int nb = gridDim.x / 48;        // blocks per slice
    if (rb * 4 >= T) return;

    const int tid = threadIdx.x;
    const int lane = tid & 63;
    const int w = tid >> 6;
    const int q = lane >> 4;
    const int ln = lane & 15;

    __shared__ short wsm[2 * 32 * 512];   // 64 KiB: wl half | wr half (swizzled)
    {
        const int gp = s >> 1, rh = s & 1;
        const short* gwl = wlb + (((size_t)gp * 64 + rh * 32) << 9);
        const short* gwr = wrb + (((size_t)gp * 64 + rh * 32) << 9);
        for (int i = tid; i < 2048; i += 256) {
            const int byte = i << 4;
            *(short8*)((char*)wsm + SWZ(byte)) = *(const short8*)((const char*)gwl + byte);
            *(short8*)((char*)wsm + 32768 + SWZ(byte)) = *(const short8*)((const char*)gwr + byte);
        }
    }
    __syncthreads();

    for (int tile = rb * 4 + w; tile < T; tile += nb * 4) {
        const int mr0 = tile << 4;
        const int ar = mr0 + ln;
        const u32 pk = list[base + (ar < M ? ar : M - 1)];
        const int bb = pk >> 18, tt = (pk >> 9) & 511, pp = pk & 511;
        const short* aE = embb + ((size_t)((bb << 9) | tt) << 9);
        const short* aH = h_bf + ((size_t)((bb << 9) | pp) << 9);

        f32x4 aL[2], aR[2];
#pragma unroll
        for (int nt = 0; nt < 2; nt++) {
            aL[nt] = {0.f, 0.f, 0.f, 0.f};
            aR[nt] = {0.f, 0.f, 0.f, 0.f};
        }
        for (int ks = 0; ks < 16; ks++) {
            const int k0 = (ks << 5) + (q << 3);
            const short8 e = *(const short8*)(aE + k0);
            const short8 h = *(const short8*)(aH + k0);
#pragma unroll
            for (int nt = 0; nt < 2; nt++) {
                const int byte = (((nt << 4) + ln) << 10) + (k0 << 1);
                const short8 bL = *(const short8*)((const char*)wsm + SWZ(byte));
                const short8 bR = *(const short8*)((const char*)wsm + 32768 + SWZ(byte));
                aL[nt] = MFMA16(e, bL, aL[nt]);
                aR[nt] = MFMA16(h, bR, aR[nt]);
            }
        }
#pragma unroll
        for (int reg = 0; reg < 4; reg++) {
            float v = aL[0][reg] * aR[0][reg] + aL[1][reg] * aR[1][reg];
            v += __shfl_xor(v, 1, 64);
            v += __shfl_xor(v, 2, 64);
            v += __shfl_xor(v, 4, 64);
            v += __shfl_xor(v, 8, 64);
            if (ln == 0) {
                const int mr = mr0 + (q << 2) + reg;
                if (mr < M) pooled2[(size_t)mr * 48 + s] = v;
            }
        }
    }
}

// ---------------------------------------------------------------------------
// gemm_lin_kernel: lin terms as a proper LDS-tiled GEMM + fused LSTM epilogue.
// C[M][1536] = [E|H] @ [ul;ur]  (H half skipped at lvl 0)
// BM=128, BN=192 (= 3 gates x 64 h-cols -> all gates of (row,h) land in one
// lane => epilogue fully fused), BK=64, 4 waves, double-buffered LDS (80 KiB,
// 2 blocks/CU). Staging via global_load_lds with per-lane gathered sources
// (rows come straight from list[] - no pack kernel). Read-side XOR swizzle
// ((row&7)<<4) keeps ds_read_b128 conflict-free.
// Grid: bid&7 = column-group (h-cols cg*64..+63, B-panel L2-resident per XCD);
// bid>>3 grid-strides over 128-row tiles.
// ---------------------------------------------------------------------------
__global__ __launch_bounds__(256, 2) void gemm_lin_kernel(
    const int lvl,
    const short* __restrict__ embb,
    const short* __restrict__ ulb,
    const short* __restrict__ urb,
    const float* __restrict__ wo,
    const float* __restrict__ bias,
    const int* __restrict__ offs,
    const u32* __restrict__ list,
    const float* __restrict__ pooled2,
    float* __restrict__ h_out,    // d_out fp32
    short* __restrict__ h_bf,     // ws bf16 (gather source + this level's writes)
    short* __restrict__ c_bf)     // ws bf16
{
    const int base = offs[lvl];
    const int M = offs[lvl + 1] - base;
    if (M <= 0) return;
    const int nt = (M + 127) >> 7;           // 128-row tiles
    const int nkc = (lvl > 0) ? 16 : 8;      // 64-k chunks (E:0..7, H:8..15)

    // [buf][ A 16384 B | B-panel 24576 B ]
    __shared__ __attribute__((aligned(16))) char lds[2][40960];

    const int tid = threadIdx.x;
    const int lane = tid & 63;
    const int w = tid >> 6;                  // wave 0..3
    const int q = lane >> 4;
    const int ln = lane & 15;
    const int cg = blockIdx.x & 7;           // h-col group
    const int swzc = (ln & 7) << 4;          // read-side swizzle constant

    // B-panel source pointers (per lane, fixed per block): 6 stage slots
    const char* pUL[6];
    const char* pUR[6];
#pragma unroll
    for (int c = 0; c < 6; c++) {
        const int d = (((w * 6 + c) << 6) + lane) << 4;   // dest byte in B tile
        const int u = d ^ (((d >> 7) & 7) << 4);          // logical byte
        const int p = u >> 7;                             // B row 0..191
        const int koff = u & 127;
        const int row = ((p >> 6) << 9) + (cg << 6) + (p & 63);  // g*512 + h
        pUL[c] = (const char*)ulb + ((size_t)row << 10) + koff;
        pUR[c] = (const char*)urb + ((size_t)row << 10) + koff;
    }
    // A-tile dest-slot decode (per lane, fixed): 4 stage slots
    int arow[4], akoff[4];
#pragma unroll
    for (int c = 0; c < 4; c++) {
        const int d = (((w * 4 + c) << 6) + lane) << 4;
        const int u = d ^ (((d >> 7) & 7) << 4);
        arow[c] = u >> 7;                                 // 0..127
        akoff[c] = u & 127;
    }

    const int wrow0 = w << 5;                // wave's 32 rows

    for (int tm = blockIdx.x >> 3; tm < nt; tm += gridDim.x >> 3) {
        const int m0 = tm << 7;
        // A source pointers for this tile (gathered rows)
        const char* pE[4];
        const char* pH[4];
#pragma unroll
        for (int c = 0; c < 4; c++) {
            int mr = m0 + arow[c];
            if (mr > M - 1) mr = M - 1;      // pad rows duplicate row M-1
            const u32 pk = list[base + mr];
            const int bb = pk >> 18, tt = (pk >> 9) & 511, pp = pk & 511;
            pE[c] = (const char*)embb + (((size_t)((bb << 9) | tt)) << 10) + akoff[c];
            pH[c] = (const char*)h_bf + (((size_t)((bb << 9) | pp)) << 10) + akoff[c];
        }

        f32x4 acc[2][12];
#pragma unroll
        for (int ms = 0; ms < 2; ms++)
#pragma unroll
            for (int j = 0; j < 12; j++)
                acc[ms][j] = {0.f, 0.f, 0.f, 0.f};

        // prologue: stage chunk 0 into buf 0
        {
            char* LA = lds[0];
            char* LB = lds[0] + 16384;
#pragma unroll
            for (int c = 0; c < 4; c++)
                gl16(pE[c], LA + (((w << 2) + c) << 10));
#pragma unroll
            for (int c = 0; c < 6; c++)
                gl16(pUL[c], LB + ((w * 6 + c) << 10));
        }
        __syncthreads();

        for (int kc = 0; kc < nkc; kc++) {
            // issue next chunk's stage (counted into the barrier drain)
            if (kc + 1 < nkc) {
                const int kn = kc + 1;
                const int cb = (kn & 7) << 7;             // 128B k-step
                char* LA = lds[kn & 1];
                char* LB = lds[kn & 1] + 16384;
                if (kn < 8) {
#pragma unroll
                    for (int c = 0; c < 4; c++)
                        gl16(pE[c] + cb, LA + (((w << 2) + c) << 10));
#pragma unroll
                    for (int c = 0; c < 6; c++)
                        gl16(pUL[c] + cb, LB + ((w * 6 + c) << 10));
                } else {
#pragma unroll
                    for (int c = 0; c < 4; c++)
                        gl16(pH[c] + cb, LA + (((w << 2) + c) << 10));
#pragma unroll
                    for (int c = 0; c < 6; c++)
                        gl16(pUR[c] + cb, LB + ((w * 6 + c) << 10));
                }
            }
            // compute from buf kc&1
            const char* LA = lds[kc & 1];
            const char* LB = lds[kc & 1] + 16384;
#pragma unroll
            for (int ks = 0; ks < 2; ks++) {
                const int kb = (ks << 6) + (q << 4);
                const short8 af0 = *(const short8*)(LA + ((((wrow0 + ln) << 7) + kb) ^ swzc));
                const short8 af1 = *(const short8*)(LA + ((((wrow0 + 16 + ln) << 7) + kb) ^ swzc));
#pragma unroll
                for (int j = 0; j < 12; j++) {
                    const short8 bf = *(const short8*)(LB + ((((j * 16 + ln) << 7) + kb) ^ swzc));
                    acc[0][j] = MFMA16(af0, bf, acc[0][j]);
                    acc[1][j] = MFMA16(af1, bf, acc[1][j]);
                }
            }
            __syncthreads();   // drains vmcnt (staged chunk ready) + lds reads
        }

        // fused epilogue: lane holds all 3 gates of its (row, h)
#pragma unroll
        for (int ms = 0; ms < 2; ms++) {
#pragma unroll
            for (int reg = 0; reg < 4; reg++) {
                const int mr = m0 + wrow0 + (ms << 4) + (q << 2) + reg;
                if (mr >= M) continue;       // pad rows never write
                const u32 pk = list[base + mr];
                const int bb = pk >> 18, tt = (pk >> 9) & 511, pp2 = pk & 511;
                const float* pr = pooled2 + (size_t)mr * 48;
                const size_t orow = ((size_t)((bb << 9) | tt)) << 9;
                const size_t prow = ((size_t)((bb << 9) | pp2)) << 9;
#pragma unroll
                for (int jh = 0; jh < 4; jh++) {
                    const int h = (cg << 6) + (jh << 4) + ln;
                    float v[3];
#pragma unroll
                    for (int g = 0; g < 3; g++) {
                        float x = acc[ms][(g << 2) + jh][reg] + bias[(g << 9) + h];
                        if (lvl > 0) {
                            const float* wop = wo + ((size_t)((g << 9) + h) << 3);
                            float sdot = 0.f;
#pragma unroll
                            for (int p2 = 0; p2 < 8; p2++)
                                sdot += (pr[(g << 4) + p2 * 2] + pr[(g << 4) + p2 * 2 + 1]) * wop[p2];
                            x += sdot;
                        }
                        // clamp + NaN-sanitize (min/max drop NaN on AMD)
                        v[g] = fclamp(x, -30.f, 30.f);
                    }
                    const float fg = fsig(v[0]);
                    const float og = fsig(v[1]);
                    const float zg = ftanh(v[2]);
                    float pc = 0.f;
                    if (lvl > 0) {
                        pc = bf2f(c_bf[prow + h]);
                        pc = fclamp(pc, -1.f, 1.f);  // |c|<=1 by induction
                    }
                    const float cc = pc * fg + (1.f - fg) * zg;
                    const float hh = og * ftanh(cc);
                    c_bf[orow + h] = f2bf(cc);
                    h_bf[orow + h] = f2bf(hh);
                    h_out[orow + h] = hh;
                }
            }
        }
    }
}

extern "C" void kernel_launch(void* const* d_in, const int* in_sizes, int n_in,
                              void* d_out, int out_size, void* d_ws, size_t ws_size,
                              hipStream_t stream) {
    const float* emb  = (const float*)d_in[0];  // (B,N,IN) fp32
    const int*   conn = (const int*)d_in[1];    // (B,N) int32
    // d_in[2] node_mask: all ones, unused
    const float* wl   = (const float*)d_in[3];  // (3,8,64,512) fp32
    const float* wr   = (const float*)d_in[4];  // (3,8,64,512) fp32
    const float* wo   = (const float*)d_in[5];  // (3,512,8)    fp32
    const float* ul   = (const float*)d_in[6];  // (3,512,512)  fp32
    const float* ur   = (const float*)d_in[7];  // (3,512,512)  fp32
    const float* bias = (const float*)d_in[8];  // (3,512)      fp32

    char* ws = (char*)d_ws;
    int* offs   = (int*)ws;          // 520
    int* counts = offs + 520;        // 520
    int* cursor = counts + 520;      // 520
    unsigned char* lvl_g = (unsigned char*)(ws + 8192);   // 64 KiB
    u32* list = (u32*)(ws + 8192 + 65536);                // 256 KiB
    // bf16 staging (byte offsets from ws base):
    short* wlb = (short*)(ws + 335872);                   // 786432 el
    short* wrb = wlb + 786432;
    short* ulb = wrb + 786432;
    short* urb = ulb + 786432;                            // ends ~6.6 MB
    short* embb = (short*)(ws + (8u << 20));              // 64 MiB
    short* h_bf = (short*)(ws + (8u << 20) + 67108864u);
    short* c_bf = (short*)(ws + (8u << 20) + 134217728u); // ends at 200 MiB
    float* pooled2 = (float*)(ws + 209715200ull);         // 12.6 MB (needs ws >= 213 MiB)

    float* h_out = (float*)d_out;

    // fp32 -> bf16 staging
    conv_kernel<<<dim3(2048), dim3(256), 0, stream>>>(emb, embb, NODES * 512 / 4);
    conv_kernel<<<dim3(256), dim3(256), 0, stream>>>(wl, wlb, 786432 / 4);
    conv_kernel<<<dim3(256), dim3(256), 0, stream>>>(wr, wrb, 786432 / 4);
    conv_kernel<<<dim3(256), dim3(256), 0, stream>>>(ul, ulb, 786432 / 4);
    conv_kernel<<<dim3(256), dim3(256), 0, stream>>>(ur, urb, 786432 / 4);

    // parallel setup: zero -> depth(pointer doubling)+hist -> scan -> scatter
    zero_kernel<<<dim3(3), dim3(256), 0, stream>>>(counts);
    depth_kernel<<<dim3(NB), dim3(256), 0, stream>>>(conn, lvl_g, counts);
    scan_kernel<<<dim3(1), dim3(256), 0, stream>>>(counts, offs, cursor);
    scatter_kernel<<<dim3(256), dim3(256), 0, stream>>>(conn, lvl_g, cursor, list);

    for (int l = 0; l < NLEVELS; l++) {
        if (l > 0)
            pool_kernel<<<dim3(480), dim3(256), 0, stream>>>(
                l, embb, wlb, wrb, h_bf, offs, list, pooled2);
        gemm_lin_kernel<<<dim3(512), dim3(256), 0, stream>>>(
            l, embb, ulb, urb, wo, bias, offs, list, pooled2, h_out, h_bf, c_bf);
    }
}

// Round 4
// 2600.247 us; speedup vs baseline: 3.6638x; 1.6268x over previous
//
#include <hip/hip_runtime.h>

#define NB 128
#define NN 512
#define NODES (NB * NN)
#define NLEVELS 64

typedef __attribute__((ext_vector_type(8))) short short8;
typedef __attribute__((ext_vector_type(4))) short short4v;
typedef __attribute__((ext_vector_type(4))) float f32x4;
typedef unsigned int u32;

__device__ __forceinline__ float bf2f(short s) {
    union { u32 u; float f; } v;
    v.u = ((u32)(unsigned short)s) << 16;
    return v.f;
}
__device__ __forceinline__ short f2bf(float f) {
    union { u32 u; float f; } v;
    v.f = f;
    u32 u = v.u + 0x7FFFu + ((v.u >> 16) & 1u);  // RNE
    return (short)(u >> 16);
}
// clamp that also sanitizes NaN (AMD v_min/v_max return the non-NaN operand)
__device__ __forceinline__ float fclamp(float x, float lo, float hi) {
    return fminf(fmaxf(x, lo), hi);
}
__device__ __forceinline__ float fsig(float x) {
    return __builtin_amdgcn_rcpf(1.f + __builtin_amdgcn_exp2f(-1.44269504f * x));
}
__device__ __forceinline__ float ftanh(float x) {
    return 1.f - 2.f * __builtin_amdgcn_rcpf(1.f + __builtin_amdgcn_exp2f(2.88539008f * x));
}
#define MFMA16(a, b, c) __builtin_amdgcn_mfma_f32_16x16x32_bf16((a), (b), (c), 0, 0, 0)

// async global->LDS 16B (per-lane global source, wave-uniform LDS dest + lane*16)
__device__ __forceinline__ void gl16(const void* g, void* l) {
    __builtin_amdgcn_global_load_lds(
        (const __attribute__((address_space(1))) unsigned int*)g,
        (__attribute__((address_space(3))) unsigned int*)l,
        16, 0, 0);
}

// ---------------------------------------------------------------------------
// fp32 -> bf16 (RNE) bulk converter, float4-vectorized grid-stride.
// ---------------------------------------------------------------------------
__global__ __launch_bounds__(256) void conv_kernel(
    const float* __restrict__ src, short* __restrict__ dst, int n4)
{
    int i = blockIdx.x * blockDim.x + threadIdx.x;
    const int stride = gridDim.x * blockDim.x;
    for (; i < n4; i += stride) {
        const f32x4 v = *(const f32x4*)(src + (size_t)i * 4);
        short4v o;
        o[0] = f2bf(v[0]); o[1] = f2bf(v[1]); o[2] = f2bf(v[2]); o[3] = f2bf(v[3]);
        *(short4v*)(dst + (size_t)i * 4) = o;
    }
}

// ---------------------------------------------------------------------------
// Setup (parallel): zero -> depth (pointer doubling, 1 block/tree) -> scan ->
// scatter into level-sorted list. list entry: b<<18 | t<<9 | par
// ---------------------------------------------------------------------------
__global__ __launch_bounds__(256) void zero_kernel(int* __restrict__ counts)
{
    const int i = blockIdx.x * 256 + threadIdx.x;
    if (i < 520) counts[i] = 0;
}

__global__ __launch_bounds__(256) void depth_kernel(
    const int* __restrict__ conn,
    unsigned char* __restrict__ lvl_g,  // [NODES]
    int* __restrict__ counts)           // [520]
{
    __shared__ short anc[NN];
    __shared__ short dep[NN];
    __shared__ int hist[520];
    const int b = blockIdx.x;
    const int tid = threadIdx.x;

    for (int i = tid; i < 520; i += 256) hist[i] = 0;
    for (int i = tid; i < NN; i += 256) {
        anc[i] = (i == 0) ? (short)0 : (short)conn[b * NN + i];  // par < i
        dep[i] = (i == 0) ? (short)0 : (short)1;
    }
    __syncthreads();
    for (int it = 0; it < 9; it++) {
        const int i0 = tid, i1 = tid + 256;
        const short a0 = anc[i0], d0 = dep[i0];
        const short a1 = anc[i1], d1 = dep[i1];
        const short da0 = dep[a0], aa0 = anc[a0];
        const short da1 = dep[a1], aa1 = anc[a1];
        __syncthreads();
        dep[i0] = (short)(d0 + da0); anc[i0] = aa0;
        dep[i1] = (short)(d1 + da1); anc[i1] = aa1;
        __syncthreads();
    }
    for (int i = tid; i < NN; i += 256) {
        const unsigned char d = (unsigned char)dep[i];
        lvl_g[b * NN + i] = d;
        atomicAdd(&hist[d], 1);
    }
    __syncthreads();
    for (int i = tid; i < 520; i += 256)
        if (hist[i]) atomicAdd(&counts[i], hist[i]);
}

__global__ __launch_bounds__(256) void scan_kernel(
    const int* __restrict__ counts,
    int* __restrict__ offs,
    int* __restrict__ cursor)
{
    __shared__ int c[520];
    __shared__ int o[520];
    const int tid = threadIdx.x;
    for (int i = tid; i < 520; i += 256) c[i] = counts[i];
    __syncthreads();
    if (tid == 0) {
        int acc = 0;
        for (int l = 0; l < 520; l++) { o[l] = acc; acc += c[l]; }
    }
    __syncthreads();
    for (int i = tid; i < 520; i += 256) {
        offs[i] = o[i];
        cursor[i] = o[i];
    }
}

__global__ __launch_bounds__(256) void scatter_kernel(
    const int* __restrict__ conn,
    const unsigned char* __restrict__ lvl_g,
    int* __restrict__ cursor,
    u32* __restrict__ list)
{
    int i = blockIdx.x * 256 + threadIdx.x;
    const int stride = gridDim.x * 256;
    for (; i < NODES; i += stride) {
        const int b = i >> 9, t = i & 511;
        const int l = lvl_g[i];
        const int par = (t == 0) ? 0 : conn[i];
        const int pos = atomicAdd(&cursor[l], 1);
        list[pos] = ((u32)b << 18) | ((u32)t << 9) | (u32)par;
    }
}

// ---------------------------------------------------------------------------
// pool_kernel (GEMM-structured): pooled[m, gp] = sum_r (E.wl^T)*(H.wr^T).
// Slice = one gp (24 slices; 24 % 8 == 0 => each slice's blocks land on one
// XCD, wl/wr slice stays L2-pinned). BM=64 rows, BK=64; 4 LDS buffers
// (Ae/Ah/Bl/Br, 8 KB each) double-buffered = 64 KiB (2 blocks/CU).
// Staging via global_load_lds with inverse-swizzled per-lane sources (A rows
// gathered from list; fully coalesced 1 KB row segments). Reads are
// XOR-swizzled ds_read_b128 (conflict-free). The r-reduction (64 cols) is
// fused in-register: per-lane product over 4 col-frags + 4-step shfl.
// Output: pooled2[m*24 + gp]. Only launched for lvl > 0.
// ---------------------------------------------------------------------------
__global__ __launch_bounds__(256, 2) void pool_kernel(
    const int lvl,
    const short* __restrict__ embb,
    const short* __restrict__ wlb,
    const short* __restrict__ wrb,
    const short* __restrict__ h_bf,
    const int* __restrict__ offs,
    const u32* __restrict__ list,
    float* __restrict__ pooled2)      // [m][24]
{
    const int base = offs[lvl];
    const int M = offs[lvl + 1] - base;
    if (M <= 0) return;
    const int nt = (M + 63) >> 6;     // 64-row tiles

    const int s = blockIdx.x % 24;    // gp slice
    const int rb = blockIdx.x / 24;
    const int nb = gridDim.x / 24;
    if (rb >= nt) return;

    // [buf]: Ae 8KB | Ah 8KB | Bl 8KB | Br 8KB
    __shared__ __attribute__((aligned(16))) char lds[2][32768];

    const int tid = threadIdx.x;
    const int l = tid & 63;
    const int w = tid >> 6;           // wave 0..3
    const int q = l >> 4;
    const int ln = l & 15;

    // B sources (fixed per block): wave w stages slots {2w, 2w+1} of Bl/Br.
    // slot j covers cols j*8..j*8+7; lane's logical (col, koff) after inverse
    // swizzle: col = j*8 + (l>>3), koff = ((l&7) ^ (col&7)) << 4.
    const char* pBl[2];
    const char* pBr[2];
#pragma unroll
    for (int cc = 0; cc < 2; cc++) {
        const int col = ((2 * w + cc) << 3) + (l >> 3);
        const int koff = ((l & 7) ^ (col & 7)) << 4;
        pBl[cc] = (const char*)wlb + (((size_t)(s * 64 + col)) << 10) + koff;
        pBr[cc] = (const char*)wrb + (((size_t)(s * 64 + col)) << 10) + koff;
    }

    for (int tm = rb; tm < nt; tm += nb) {
        const int m0 = tm << 6;
        // A sources for this tile (rows gathered via list; same slot scheme)
        const char* pAe[2];
        const char* pAh[2];
#pragma unroll
        for (int cc = 0; cc < 2; cc++) {
            const int row = ((2 * w + cc) << 3) + (l >> 3);
            const int koff = ((l & 7) ^ (row & 7)) << 4;
            int mr = m0 + row; if (mr > M - 1) mr = M - 1;   // pad rows dup M-1
            const u32 pk = list[base + mr];
            const int bb = pk >> 18, tt = (pk >> 9) & 511, pp = pk & 511;
            pAe[cc] = (const char*)embb + (((size_t)((bb << 9) | tt)) << 10) + koff;
            pAh[cc] = (const char*)h_bf + (((size_t)((bb << 9) | pp)) << 10) + koff;
        }

        f32x4 accL[4], accR[4];
#pragma unroll
        for (int j = 0; j < 4; j++) {
            accL[j] = {0.f, 0.f, 0.f, 0.f};
            accR[j] = {0.f, 0.f, 0.f, 0.f};
        }

        // prologue: stage chunk 0 into buf 0
        {
            char* L = lds[0];
#pragma unroll
            for (int cc = 0; cc < 2; cc++) {
                const int slot = (2 * w + cc) << 10;
                gl16(pAe[cc], L + slot);
                gl16(pAh[cc], L + 8192 + slot);
                gl16(pBl[cc], L + 16384 + slot);
                gl16(pBr[cc], L + 24576 + slot);
            }
        }
        __syncthreads();

        for (int c = 0; c < 8; c++) {
            if (c < 7) {
                char* L = lds[(c + 1) & 1];
                const int cb = (c + 1) << 7;     // 128B per 64-k chunk
#pragma unroll
                for (int cc = 0; cc < 2; cc++) {
                    const int slot = (2 * w + cc) << 10;
                    gl16(pAe[cc] + cb, L + slot);
                    gl16(pAh[cc] + cb, L + 8192 + slot);
                    gl16(pBl[cc] + cb, L + 16384 + slot);
                    gl16(pBr[cc] + cb, L + 24576 + slot);
                }
            }
            const char* L = lds[c & 1];
#pragma unroll
            for (int kf = 0; kf < 2; kf++) {
                const int abyte = (((w << 4) + ln) << 7) + (kf << 6) + (q << 4);
                const int aswz = abyte ^ ((ln & 7) << 4);
                const short8 ae = *(const short8*)(L + aswz);
                const short8 ah = *(const short8*)(L + 8192 + aswz);
#pragma unroll
                for (int j = 0; j < 4; j++) {
                    const int bbyte = (((j << 4) + ln) << 7) + (kf << 6) + (q << 4);
                    const int bswz = bbyte ^ ((ln & 7) << 4);
                    const short8 bl = *(const short8*)(L + 16384 + bswz);
                    const short8 br = *(const short8*)(L + 24576 + bswz);
                    accL[j] = MFMA16(ae, bl, accL[j]);
                    accR[j] = MFMA16(ah, br, accR[j]);
                }
            }
            __syncthreads();   // staged chunk ready + LDS reads drained
        }

        // epilogue: reduce product over the 64 r-cols; write pooled2[m*24+s]
#pragma unroll
        for (int reg = 0; reg < 4; reg++) {
            float v = accL[0][reg] * accR[0][reg] + accL[1][reg] * accR[1][reg]
                    + accL[2][reg] * accR[2][reg] + accL[3][reg] * accR[3][reg];
            v += __shfl_xor(v, 1, 64);
            v += __shfl_xor(v, 2, 64);
            v += __shfl_xor(v, 4, 64);
            v += __shfl_xor(v, 8, 64);
            if (ln == 0) {
                const int mr = m0 + (w << 4) + (q << 2) + reg;
                if (mr < M) pooled2[(size_t)mr * 24 + s] = v;
            }
        }
    }
}

// ---------------------------------------------------------------------------
// gemm_lin_kernel: lin terms as a proper LDS-tiled GEMM + fused LSTM epilogue.
// C[M][1536] = [E|H] @ [ul;ur]  (H half skipped at lvl 0)
// BM=128, BN=192 (= 3 gates x 64 h-cols -> all gates of (row,h) land in one
// lane => epilogue fully fused), BK=64, 4 waves, double-buffered LDS (80 KiB,
// 2 blocks/CU). Staging via global_load_lds with per-lane gathered sources.
// Read-side XOR swizzle ((row&7)<<4) keeps ds_read_b128 conflict-free.
// ---------------------------------------------------------------------------
__global__ __launch_bounds__(256, 2) void gemm_lin_kernel(
    const int lvl,
    const short* __restrict__ embb,
    const short* __restrict__ ulb,
    const short* __restrict__ urb,
    const float* __restrict__ wo,
    const float* __restrict__ bias,
    const int* __restrict__ offs,
    const u32* __restrict__ list,
    const float* __restrict__ pooled2,
    float* __restrict__ h_out,    // d_out fp32
    short* __restrict__ h_bf,     // ws bf16 (gather source + this level's writes)
    short* __restrict__ c_bf)     // ws bf16
{
    const int base = offs[lvl];
    const int M = offs[lvl + 1] - base;
    if (M <= 0) return;
    const int nt = (M + 127) >> 7;           // 128-row tiles
    const int nkc = (lvl > 0) ? 16 : 8;      // 64-k chunks (E:0..7, H:8..15)

    // [buf][ A 16384 B | B-panel 24576 B ]
    __shared__ __attribute__((aligned(16))) char lds[2][40960];

    const int tid = threadIdx.x;
    const int lane = tid & 63;
    const int w = tid >> 6;                  // wave 0..3
    const int q = lane >> 4;
    const int ln = lane & 15;
    const int cg = blockIdx.x & 7;           // h-col group
    const int swzc = (ln & 7) << 4;          // read-side swizzle constant

    // B-panel source pointers (per lane, fixed per block): 6 stage slots
    const char* pUL[6];
    const char* pUR[6];
#pragma unroll
    for (int c = 0; c < 6; c++) {
        const int d = (((w * 6 + c) << 6) + lane) << 4;   // dest byte in B tile
        const int u = d ^ (((d >> 7) & 7) << 4);          // logical byte
        const int p = u >> 7;                             // B row 0..191
        const int koff = u & 127;
        const int row = ((p >> 6) << 9) + (cg << 6) + (p & 63);  // g*512 + h
        pUL[c] = (const char*)ulb + ((size_t)row << 10) + koff;
        pUR[c] = (const char*)urb + ((size_t)row << 10) + koff;
    }
    // A-tile dest-slot decode (per lane, fixed): 4 stage slots
    int arow[4], akoff[4];
#pragma unroll
    for (int c = 0; c < 4; c++) {
        const int d = (((w * 4 + c) << 6) + lane) << 4;
        const int u = d ^ (((d >> 7) & 7) << 4);
        arow[c] = u >> 7;                                 // 0..127
        akoff[c] = u & 127;
    }

    const int wrow0 = w << 5;                // wave's 32 rows

    for (int tm = blockIdx.x >> 3; tm < nt; tm += gridDim.x >> 3) {
        const int m0 = tm << 7;
        // A source pointers for this tile (gathered rows)
        const char* pE[4];
        const char* pH[4];
#pragma unroll
        for (int c = 0; c < 4; c++) {
            int mr = m0 + arow[c];
            if (mr > M - 1) mr = M - 1;      // pad rows duplicate row M-1
            const u32 pk = list[base + mr];
            const int bb = pk >> 18, tt = (pk >> 9) & 511, pp = pk & 511;
            pE[c] = (const char*)embb + (((size_t)((bb << 9) | tt)) << 10) + akoff[c];
            pH[c] = (const char*)h_bf + (((size_t)((bb << 9) | pp)) << 10) + akoff[c];
        }

        f32x4 acc[2][12];
#pragma unroll
        for (int ms = 0; ms < 2; ms++)
#pragma unroll
            for (int j = 0; j < 12; j++)
                acc[ms][j] = {0.f, 0.f, 0.f, 0.f};

        // prologue: stage chunk 0 into buf 0
        {
            char* LA = lds[0];
            char* LB = lds[0] + 16384;
#pragma unroll
            for (int c = 0; c < 4; c++)
                gl16(pE[c], LA + (((w << 2) + c) << 10));
#pragma unroll
            for (int c = 0; c < 6; c++)
                gl16(pUL[c], LB + ((w * 6 + c) << 10));
        }
        __syncthreads();

        for (int kc = 0; kc < nkc; kc++) {
            // issue next chunk's stage (counted into the barrier drain)
            if (kc + 1 < nkc) {
                const int kn = kc + 1;
                const int cb = (kn & 7) << 7;             // 128B k-step
                char* LA = lds[kn & 1];
                char* LB = lds[kn & 1] + 16384;
                if (kn < 8) {
#pragma unroll
                    for (int c = 0; c < 4; c++)
                        gl16(pE[c] + cb, LA + (((w << 2) + c) << 10));
#pragma unroll
                    for (int c = 0; c < 6; c++)
                        gl16(pUL[c] + cb, LB + ((w * 6 + c) << 10));
                } else {
#pragma unroll
                    for (int c = 0; c < 4; c++)
                        gl16(pH[c] + cb, LA + (((w << 2) + c) << 10));
#pragma unroll
                    for (int c = 0; c < 6; c++)
                        gl16(pUR[c] + cb, LB + ((w * 6 + c) << 10));
                }
            }
            // compute from buf kc&1
            const char* LA = lds[kc & 1];
            const char* LB = lds[kc & 1] + 16384;
#pragma unroll
            for (int ks = 0; ks < 2; ks++) {
                const int kb = (ks << 6) + (q << 4);
                const short8 af0 = *(const short8*)(LA + ((((wrow0 + ln) << 7) + kb) ^ swzc));
                const short8 af1 = *(const short8*)(LA + ((((wrow0 + 16 + ln) << 7) + kb) ^ swzc));
#pragma unroll
                for (int j = 0; j < 12; j++) {
                    const short8 bf = *(const short8*)(LB + ((((j * 16 + ln) << 7) + kb) ^ swzc));
                    acc[0][j] = MFMA16(af0, bf, acc[0][j]);
                    acc[1][j] = MFMA16(af1, bf, acc[1][j]);
                }
            }
            __syncthreads();   // drains vmcnt (staged chunk ready) + lds reads
        }

        // fused epilogue: lane holds all 3 gates of its (row, h)
#pragma unroll
        for (int ms = 0; ms < 2; ms++) {
#pragma unroll
            for (int reg = 0; reg < 4; reg++) {
                const int mr = m0 + wrow0 + (ms << 4) + (q << 2) + reg;
                if (mr >= M) continue;       // pad rows never write
                const u32 pk = list[base + mr];
                const int bb = pk >> 18, tt = (pk >> 9) & 511, pp2 = pk & 511;
                const float* pr = pooled2 + (size_t)mr * 24;
                const size_t orow = ((size_t)((bb << 9) | tt)) << 9;
                const size_t prow = ((size_t)((bb << 9) | pp2)) << 9;
#pragma unroll
                for (int jh = 0; jh < 4; jh++) {
                    const int h = (cg << 6) + (jh << 4) + ln;
                    float v[3];
#pragma unroll
                    for (int g = 0; g < 3; g++) {
                        float x = acc[ms][(g << 2) + jh][reg] + bias[(g << 9) + h];
                        if (lvl > 0) {
                            const float* wop = wo + ((size_t)((g << 9) + h) << 3);
                            float sdot = 0.f;
#pragma unroll
                            for (int p2 = 0; p2 < 8; p2++)
                                sdot += pr[(g << 3) + p2] * wop[p2];
                            x += sdot;
                        }
                        // clamp + NaN-sanitize (min/max drop NaN on AMD)
                        v[g] = fclamp(x, -30.f, 30.f);
                    }
                    const float fg = fsig(v[0]);
                    const float og = fsig(v[1]);
                    const float zg = ftanh(v[2]);
                    float pc = 0.f;
                    if (lvl > 0) {
                        pc = bf2f(c_bf[prow + h]);
                        pc = fclamp(pc, -1.f, 1.f);  // |c|<=1 by induction
                    }
                    const float cc = pc * fg + (1.f - fg) * zg;
                    const float hh = og * ftanh(cc);
                    c_bf[orow + h] = f2bf(cc);
                    h_bf[orow + h] = f2bf(hh);
                    h_out[orow + h] = hh;
                }
            }
        }
    }
}

extern "C" void kernel_launch(void* const* d_in, const int* in_sizes, int n_in,
                              void* d_out, int out_size, void* d_ws, size_t ws_size,
                              hipStream_t stream) {
    const float* emb  = (const float*)d_in[0];  // (B,N,IN) fp32
    const int*   conn = (const int*)d_in[1];    // (B,N) int32
    // d_in[2] node_mask: all ones, unused
    const float* wl   = (const float*)d_in[3];  // (3,8,64,512) fp32
    const float* wr   = (const float*)d_in[4];  // (3,8,64,512) fp32
    const float* wo   = (const float*)d_in[5];  // (3,512,8)    fp32
    const float* ul   = (const float*)d_in[6];  // (3,512,512)  fp32
    const float* ur   = (const float*)d_in[7];  // (3,512,512)  fp32
    const float* bias = (const float*)d_in[8];  // (3,512)      fp32

    char* ws = (char*)d_ws;
    int* offs   = (int*)ws;          // 520
    int* counts = offs + 520;        // 520
    int* cursor = counts + 520;      // 520
    unsigned char* lvl_g = (unsigned char*)(ws + 8192);   // 64 KiB
    u32* list = (u32*)(ws + 8192 + 65536);                // 256 KiB
    // bf16 staging (byte offsets from ws base):
    short* wlb = (short*)(ws + 335872);                   // 786432 el
    short* wrb = wlb + 786432;
    short* ulb = wrb + 786432;
    short* urb = ulb + 786432;                            // ends ~6.6 MB
    short* embb = (short*)(ws + (8u << 20));              // 64 MiB
    short* h_bf = (short*)(ws + (8u << 20) + 67108864u);
    short* c_bf = (short*)(ws + (8u << 20) + 134217728u); // ends at 200 MiB
    float* pooled2 = (float*)(ws + 209715200ull);         // 6.3 MB (needs ws >= 216 MiB)

    float* h_out = (float*)d_out;

    // fp32 -> bf16 staging
    conv_kernel<<<dim3(2048), dim3(256), 0, stream>>>(emb, embb, NODES * 512 / 4);
    conv_kernel<<<dim3(256), dim3(256), 0, stream>>>(wl, wlb, 786432 / 4);
    conv_kernel<<<dim3(256), dim3(256), 0, stream>>>(wr, wrb, 786432 / 4);
    conv_kernel<<<dim3(256), dim3(256), 0, stream>>>(ul, ulb, 786432 / 4);
    conv_kernel<<<dim3(256), dim3(256), 0, stream>>>(ur, urb, 786432 / 4);

    // parallel setup: zero -> depth(pointer doubling)+hist -> scan -> scatter
    zero_kernel<<<dim3(3), dim3(256), 0, stream>>>(counts);
    depth_kernel<<<dim3(NB), dim3(256), 0, stream>>>(conn, lvl_g, counts);
    scan_kernel<<<dim3(1), dim3(256), 0, stream>>>(counts, offs, cursor);
    scatter_kernel<<<dim3(256), dim3(256), 0, stream>>>(conn, lvl_g, cursor, list);

    for (int l = 0; l < NLEVELS; l++) {
        if (l > 0)
            pool_kernel<<<dim3(480), dim3(256), 0, stream>>>(
                l, embb, wlb, wrb, h_bf, offs, list, pooled2);
        gemm_lin_kernel<<<dim3(512), dim3(256), 0, stream>>>(
            l, embb, ulb, urb, wo, bias, offs, list, pooled2, h_out, h_bf, c_bf);
    }
}

// Round 5
// 2303.442 us; speedup vs baseline: 4.1359x; 1.1289x over previous
//
#include <hip/hip_runtime.h>

#define NB 128
#define NN 512
#define NODES (NB * NN)
#define NLEVELS 64

typedef __attribute__((ext_vector_type(8))) short short8;
typedef __attribute__((ext_vector_type(4))) short short4v;
typedef __attribute__((ext_vector_type(4))) float f32x4;
typedef unsigned int u32;

__device__ __forceinline__ float bf2f(short s) {
    union { u32 u; float f; } v;
    v.u = ((u32)(unsigned short)s) << 16;
    return v.f;
}
__device__ __forceinline__ short f2bf(float f) {
    union { u32 u; float f; } v;
    v.f = f;
    u32 u = v.u + 0x7FFFu + ((v.u >> 16) & 1u);  // RNE
    return (short)(u >> 16);
}
// clamp that also sanitizes NaN (AMD v_min/v_max return the non-NaN operand)
__device__ __forceinline__ float fclamp(float x, float lo, float hi) {
    return fminf(fmaxf(x, lo), hi);
}
__device__ __forceinline__ float fsig(float x) {
    return __builtin_amdgcn_rcpf(1.f + __builtin_amdgcn_exp2f(-1.44269504f * x));
}
__device__ __forceinline__ float ftanh(float x) {
    return 1.f - 2.f * __builtin_amdgcn_rcpf(1.f + __builtin_amdgcn_exp2f(2.88539008f * x));
}
#define MFMA16(a, b, c) __builtin_amdgcn_mfma_f32_16x16x32_bf16((a), (b), (c), 0, 0, 0)

// async global->LDS 16B (per-lane global source, wave-uniform LDS dest + lane*16)
__device__ __forceinline__ void gl16(const void* g, void* l) {
    __builtin_amdgcn_global_load_lds(
        (const __attribute__((address_space(1))) unsigned int*)g,
        (__attribute__((address_space(3))) unsigned int*)l,
        16, 0, 0);
}

// ---------------------------------------------------------------------------
// fp32 -> bf16 (RNE) bulk converter, float4-vectorized grid-stride.
// ---------------------------------------------------------------------------
__global__ __launch_bounds__(256) void conv_kernel(
    const float* __restrict__ src, short* __restrict__ dst, int n4)
{
    int i = blockIdx.x * blockDim.x + threadIdx.x;
    const int stride = gridDim.x * blockDim.x;
    for (; i < n4; i += stride) {
        const f32x4 v = *(const f32x4*)(src + (size_t)i * 4);
        short4v o;
        o[0] = f2bf(v[0]); o[1] = f2bf(v[1]); o[2] = f2bf(v[2]); o[3] = f2bf(v[3]);
        *(short4v*)(dst + (size_t)i * 4) = o;
    }
}

// ---------------------------------------------------------------------------
// Setup (parallel): zero -> depth (pointer doubling, 1 block/tree) -> scan ->
// scatter into level-sorted list. list entry: b<<18 | t<<9 | par
// ---------------------------------------------------------------------------
__global__ __launch_bounds__(256) void zero_kernel(int* __restrict__ counts)
{
    const int i = blockIdx.x * 256 + threadIdx.x;
    if (i < 520) counts[i] = 0;
}

__global__ __launch_bounds__(256) void depth_kernel(
    const int* __restrict__ conn,
    unsigned char* __restrict__ lvl_g,  // [NODES]
    int* __restrict__ counts)           // [520]
{
    __shared__ short anc[NN];
    __shared__ short dep[NN];
    __shared__ int hist[520];
    const int b = blockIdx.x;
    const int tid = threadIdx.x;

    for (int i = tid; i < 520; i += 256) hist[i] = 0;
    for (int i = tid; i < NN; i += 256) {
        anc[i] = (i == 0) ? (short)0 : (short)conn[b * NN + i];  // par < i
        dep[i] = (i == 0) ? (short)0 : (short)1;
    }
    __syncthreads();
    for (int it = 0; it < 9; it++) {
        const int i0 = tid, i1 = tid + 256;
        const short a0 = anc[i0], d0 = dep[i0];
        const short a1 = anc[i1], d1 = dep[i1];
        const short da0 = dep[a0], aa0 = anc[a0];
        const short da1 = dep[a1], aa1 = anc[a1];
        __syncthreads();
        dep[i0] = (short)(d0 + da0); anc[i0] = aa0;
        dep[i1] = (short)(d1 + da1); anc[i1] = aa1;
        __syncthreads();
    }
    for (int i = tid; i < NN; i += 256) {
        const unsigned char d = (unsigned char)dep[i];
        lvl_g[b * NN + i] = d;
        atomicAdd(&hist[d], 1);
    }
    __syncthreads();
    for (int i = tid; i < 520; i += 256)
        if (hist[i]) atomicAdd(&counts[i], hist[i]);
}

__global__ __launch_bounds__(256) void scan_kernel(
    const int* __restrict__ counts,
    int* __restrict__ offs,
    int* __restrict__ cursor)
{
    __shared__ int c[520];
    __shared__ int o[520];
    const int tid = threadIdx.x;
    for (int i = tid; i < 520; i += 256) c[i] = counts[i];
    __syncthreads();
    if (tid == 0) {
        int acc = 0;
        for (int l = 0; l < 520; l++) { o[l] = acc; acc += c[l]; }
    }
    __syncthreads();
    for (int i = tid; i < 520; i += 256) {
        offs[i] = o[i];
        cursor[i] = o[i];
    }
}

// One block per tree. Local ranks via LDS atomics; ONE global atomic per
// (tree, distinct level) to reserve the block's span (kills the 65536-way
// global cursor contention that cost 270 us). Within-level order is
// arbitrary-by-design (level kernels only need the grouping).
__global__ __launch_bounds__(256) void scatter_kernel(
    const int* __restrict__ conn,
    const unsigned char* __restrict__ lvl_g,
    int* __restrict__ cursor,
    u32* __restrict__ list)
{
    __shared__ int hist[520];
    __shared__ int base_s[520];
    __shared__ short rank_s[NN];
    const int b = blockIdx.x;
    const int tid = threadIdx.x;

    for (int i = tid; i < 520; i += 256) hist[i] = 0;
    __syncthreads();
    for (int i = tid; i < NN; i += 256) {
        const int l = lvl_g[b * NN + i];
        rank_s[i] = (short)atomicAdd(&hist[l], 1);
    }
    __syncthreads();
    for (int i = tid; i < 520; i += 256) {
        const int c = hist[i];
        base_s[i] = c ? atomicAdd(&cursor[i], c) : 0;
    }
    __syncthreads();
    for (int i = tid; i < NN; i += 256) {
        const int l = lvl_g[b * NN + i];
        const int par = (i == 0) ? 0 : conn[b * NN + i];
        list[base_s[l] + rank_s[i]] = ((u32)b << 18) | ((u32)i << 9) | (u32)par;
    }
}

// ---------------------------------------------------------------------------
// pool_kernel (GEMM-structured): pooled[m, gp] = sum_r (E.wl^T)*(H.wr^T).
// Slice = one gp (24 slices; 24 % 8 == 0 => each slice's blocks land on one
// XCD, wl/wr slice stays L2-pinned). BM=64 rows, BK=64; 4 LDS buffers
// (Ae/Ah/Bl/Br, 8 KB each) double-buffered = 64 KiB (2 blocks/CU).
// Output: pooled2[m*24 + gp]. Only launched for lvl > 0.
// ---------------------------------------------------------------------------
__global__ __launch_bounds__(256, 2) void pool_kernel(
    const int lvl,
    const short* __restrict__ embb,
    const short* __restrict__ wlb,
    const short* __restrict__ wrb,
    const short* __restrict__ h_bf,
    const int* __restrict__ offs,
    const u32* __restrict__ list,
    float* __restrict__ pooled2)      // [m][24]
{
    const int base = offs[lvl];
    const int M = offs[lvl + 1] - base;
    if (M <= 0) return;
    const int nt = (M + 63) >> 6;     // 64-row tiles

    const int s = blockIdx.x % 24;    // gp slice
    const int rb = blockIdx.x / 24;
    const int nb = gridDim.x / 24;
    if (rb >= nt) return;

    // [buf]: Ae 8KB | Ah 8KB | Bl 8KB | Br 8KB
    __shared__ __attribute__((aligned(16))) char lds[2][32768];

    const int tid = threadIdx.x;
    const int l = tid & 63;
    const int w = tid >> 6;           // wave 0..3
    const int q = l >> 4;
    const int ln = l & 15;

    // B sources (fixed per block): wave w stages slots {2w, 2w+1} of Bl/Br.
    const char* pBl[2];
    const char* pBr[2];
#pragma unroll
    for (int cc = 0; cc < 2; cc++) {
        const int col = ((2 * w + cc) << 3) + (l >> 3);
        const int koff = ((l & 7) ^ (col & 7)) << 4;
        pBl[cc] = (const char*)wlb + (((size_t)(s * 64 + col)) << 10) + koff;
        pBr[cc] = (const char*)wrb + (((size_t)(s * 64 + col)) << 10) + koff;
    }

    for (int tm = rb; tm < nt; tm += nb) {
        const int m0 = tm << 6;
        // A sources for this tile (rows gathered via list; same slot scheme)
        const char* pAe[2];
        const char* pAh[2];
#pragma unroll
        for (int cc = 0; cc < 2; cc++) {
            const int row = ((2 * w + cc) << 3) + (l >> 3);
            const int koff = ((l & 7) ^ (row & 7)) << 4;
            int mr = m0 + row; if (mr > M - 1) mr = M - 1;   // pad rows dup M-1
            const u32 pk = list[base + mr];
            const int bb = pk >> 18, tt = (pk >> 9) & 511, pp = pk & 511;
            pAe[cc] = (const char*)embb + (((size_t)((bb << 9) | tt)) << 10) + koff;
            pAh[cc] = (const char*)h_bf + (((size_t)((bb << 9) | pp)) << 10) + koff;
        }

        f32x4 accL[4], accR[4];
#pragma unroll
        for (int j = 0; j < 4; j++) {
            accL[j] = {0.f, 0.f, 0.f, 0.f};
            accR[j] = {0.f, 0.f, 0.f, 0.f};
        }

        // prologue: stage chunk 0 into buf 0
        {
            char* L = lds[0];
#pragma unroll
            for (int cc = 0; cc < 2; cc++) {
                const int slot = (2 * w + cc) << 10;
                gl16(pAe[cc], L + slot);
                gl16(pAh[cc], L + 8192 + slot);
                gl16(pBl[cc], L + 16384 + slot);
                gl16(pBr[cc], L + 24576 + slot);
            }
        }
        __syncthreads();

        for (int c = 0; c < 8; c++) {
            if (c < 7) {
                char* L = lds[(c + 1) & 1];
                const int cb = (c + 1) << 7;     // 128B per 64-k chunk
#pragma unroll
                for (int cc = 0; cc < 2; cc++) {
                    const int slot = (2 * w + cc) << 10;
                    gl16(pAe[cc] + cb, L + slot);
                    gl16(pAh[cc] + cb, L + 8192 + slot);
                    gl16(pBl[cc] + cb, L + 16384 + slot);
                    gl16(pBr[cc] + cb, L + 24576 + slot);
                }
            }
            const char* L = lds[c & 1];
#pragma unroll
            for (int kf = 0; kf < 2; kf++) {
                const int abyte = (((w << 4) + ln) << 7) + (kf << 6) + (q << 4);
                const int aswz = abyte ^ ((ln & 7) << 4);
                const short8 ae = *(const short8*)(L + aswz);
                const short8 ah = *(const short8*)(L + 8192 + aswz);
#pragma unroll
                for (int j = 0; j < 4; j++) {
                    const int bbyte = (((j << 4) + ln) << 7) + (kf << 6) + (q << 4);
                    const int bswz = bbyte ^ ((ln & 7) << 4);
                    const short8 bl = *(const short8*)(L + 16384 + bswz);
                    const short8 br = *(const short8*)(L + 24576 + bswz);
                    accL[j] = MFMA16(ae, bl, accL[j]);
                    accR[j] = MFMA16(ah, br, accR[j]);
                }
            }
            __syncthreads();   // staged chunk ready + LDS reads drained
        }

        // epilogue: reduce product over the 64 r-cols; write pooled2[m*24+s]
#pragma unroll
        for (int reg = 0; reg < 4; reg++) {
            float v = accL[0][reg] * accR[0][reg] + accL[1][reg] * accR[1][reg]
                    + accL[2][reg] * accR[2][reg] + accL[3][reg] * accR[3][reg];
            v += __shfl_xor(v, 1, 64);
            v += __shfl_xor(v, 2, 64);
            v += __shfl_xor(v, 4, 64);
            v += __shfl_xor(v, 8, 64);
            if (ln == 0) {
                const int mr = m0 + (w << 4) + (q << 2) + reg;
                if (mr < M) pooled2[(size_t)mr * 24 + s] = v;
            }
        }
    }
}

// ---------------------------------------------------------------------------
// gemm_lin_kernel: lin terms as a proper LDS-tiled GEMM + fused LSTM epilogue.
// C[M][1536] = [E|H] @ [ul;ur]  (H half skipped at lvl 0)
// BM=128, BN=192, BK=64, 4 waves, double-buffered LDS (80 KiB, 2 blocks/CU).
// ---------------------------------------------------------------------------
__global__ __launch_bounds__(256, 2) void gemm_lin_kernel(
    const int lvl,
    const short* __restrict__ embb,
    const short* __restrict__ ulb,
    const short* __restrict__ urb,
    const float* __restrict__ wo,
    const float* __restrict__ bias,
    const int* __restrict__ offs,
    const u32* __restrict__ list,
    const float* __restrict__ pooled2,
    float* __restrict__ h_out,    // d_out fp32
    short* __restrict__ h_bf,     // ws bf16 (gather source + this level's writes)
    short* __restrict__ c_bf)     // ws bf16
{
    const int base = offs[lvl];
    const int M = offs[lvl + 1] - base;
    if (M <= 0) return;
    const int nt = (M + 127) >> 7;           // 128-row tiles
    const int nkc = (lvl > 0) ? 16 : 8;      // 64-k chunks (E:0..7, H:8..15)

    // [buf][ A 16384 B | B-panel 24576 B ]
    __shared__ __attribute__((aligned(16))) char lds[2][40960];

    const int tid = threadIdx.x;
    const int lane = tid & 63;
    const int w = tid >> 6;                  // wave 0..3
    const int q = lane >> 4;
    const int ln = lane & 15;
    const int cg = blockIdx.x & 7;           // h-col group
    const int swzc = (ln & 7) << 4;          // read-side swizzle constant

    // B-panel source pointers (per lane, fixed per block): 6 stage slots
    const char* pUL[6];
    const char* pUR[6];
#pragma unroll
    for (int c = 0; c < 6; c++) {
        const int d = (((w * 6 + c) << 6) + lane) << 4;   // dest byte in B tile
        const int u = d ^ (((d >> 7) & 7) << 4);          // logical byte
        const int p = u >> 7;                             // B row 0..191
        const int koff = u & 127;
        const int row = ((p >> 6) << 9) + (cg << 6) + (p & 63);  // g*512 + h
        pUL[c] = (const char*)ulb + ((size_t)row << 10) + koff;
        pUR[c] = (const char*)urb + ((size_t)row << 10) + koff;
    }
    // A-tile dest-slot decode (per lane, fixed): 4 stage slots
    int arow[4], akoff[4];
#pragma unroll
    for (int c = 0; c < 4; c++) {
        const int d = (((w * 4 + c) << 6) + lane) << 4;
        const int u = d ^ (((d >> 7) & 7) << 4);
        arow[c] = u >> 7;                                 // 0..127
        akoff[c] = u & 127;
    }

    const int wrow0 = w << 5;                // wave's 32 rows

    for (int tm = blockIdx.x >> 3; tm < nt; tm += gridDim.x >> 3) {
        const int m0 = tm << 7;
        // A source pointers for this tile (gathered rows)
        const char* pE[4];
        const char* pH[4];
#pragma unroll
        for (int c = 0; c < 4; c++) {
            int mr = m0 + arow[c];
            if (mr > M - 1) mr = M - 1;      // pad rows duplicate row M-1
            const u32 pk = list[base + mr];
            const int bb = pk >> 18, tt = (pk >> 9) & 511, pp = pk & 511;
            pE[c] = (const char*)embb + (((size_t)((bb << 9) | tt)) << 10) + akoff[c];
            pH[c] = (const char*)h_bf + (((size_t)((bb << 9) | pp)) << 10) + akoff[c];
        }

        f32x4 acc[2][12];
#pragma unroll
        for (int ms = 0; ms < 2; ms++)
#pragma unroll
            for (int j = 0; j < 12; j++)
                acc[ms][j] = {0.f, 0.f, 0.f, 0.f};

        // prologue: stage chunk 0 into buf 0
        {
            char* LA = lds[0];
            char* LB = lds[0] + 16384;
#pragma unroll
            for (int c = 0; c < 4; c++)
                gl16(pE[c], LA + (((w << 2) + c) << 10));
#pragma unroll
            for (int c = 0; c < 6; c++)
                gl16(pUL[c], LB + ((w * 6 + c) << 10));
        }
        __syncthreads();

        for (int kc = 0; kc < nkc; kc++) {
            // issue next chunk's stage (counted into the barrier drain)
            if (kc + 1 < nkc) {
                const int kn = kc + 1;
                const int cb = (kn & 7) << 7;             // 128B k-step
                char* LA = lds[kn & 1];
                char* LB = lds[kn & 1] + 16384;
                if (kn < 8) {
#pragma unroll
                    for (int c = 0; c < 4; c++)
                        gl16(pE[c] + cb, LA + (((w << 2) + c) << 10));
#pragma unroll
                    for (int c = 0; c < 6; c++)
                        gl16(pUL[c] + cb, LB + ((w * 6 + c) << 10));
                } else {
#pragma unroll
                    for (int c = 0; c < 4; c++)
                        gl16(pH[c] + cb, LA + (((w << 2) + c) << 10));
#pragma unroll
                    for (int c = 0; c < 6; c++)
                        gl16(pUR[c] + cb, LB + ((w * 6 + c) << 10));
                }
            }
            // compute from buf kc&1
            const char* LA = lds[kc & 1];
            const char* LB = lds[kc & 1] + 16384;
#pragma unroll
            for (int ks = 0; ks < 2; ks++) {
                const int kb = (ks << 6) + (q << 4);
                const short8 af0 = *(const short8*)(LA + ((((wrow0 + ln) << 7) + kb) ^ swzc));
                const short8 af1 = *(const short8*)(LA + ((((wrow0 + 16 + ln) << 7) + kb) ^ swzc));
#pragma unroll
                for (int j = 0; j < 12; j++) {
                    const short8 bf = *(const short8*)(LB + ((((j * 16 + ln) << 7) + kb) ^ swzc));
                    acc[0][j] = MFMA16(af0, bf, acc[0][j]);
                    acc[1][j] = MFMA16(af1, bf, acc[1][j]);
                }
            }
            __syncthreads();   // drains vmcnt (staged chunk ready) + lds reads
        }

        // fused epilogue: lane holds all 3 gates of its (row, h)
#pragma unroll
        for (int ms = 0; ms < 2; ms++) {
#pragma unroll
            for (int reg = 0; reg < 4; reg++) {
                const int mr = m0 + wrow0 + (ms << 4) + (q << 2) + reg;
                if (mr >= M) continue;       // pad rows never write
                const u32 pk = list[base + mr];
                const int bb = pk >> 18, tt = (pk >> 9) & 511, pp2 = pk & 511;
                const float* pr = pooled2 + (size_t)mr * 24;
                const size_t orow = ((size_t)((bb << 9) | tt)) << 9;
                const size_t prow = ((size_t)((bb << 9) | pp2)) << 9;
#pragma unroll
                for (int jh = 0; jh < 4; jh++) {
                    const int h = (cg << 6) + (jh << 4) + ln;
                    float v[3];
#pragma unroll
                    for (int g = 0; g < 3; g++) {
                        float x = acc[ms][(g << 2) + jh][reg] + bias[(g << 9) + h];
                        if (lvl > 0) {
                            const float* wop = wo + ((size_t)((g << 9) + h) << 3);
                            float sdot = 0.f;
#pragma unroll
                            for (int p2 = 0; p2 < 8; p2++)
                                sdot += pr[(g << 3) + p2] * wop[p2];
                            x += sdot;
                        }
                        // clamp + NaN-sanitize (min/max drop NaN on AMD)
                        v[g] = fclamp(x, -30.f, 30.f);
                    }
                    const float fg = fsig(v[0]);
                    const float og = fsig(v[1]);
                    const float zg = ftanh(v[2]);
                    float pc = 0.f;
                    if (lvl > 0) {
                        pc = bf2f(c_bf[prow + h]);
                        pc = fclamp(pc, -1.f, 1.f);  // |c|<=1 by induction
                    }
                    const float cc = pc * fg + (1.f - fg) * zg;
                    const float hh = og * ftanh(cc);
                    c_bf[orow + h] = f2bf(cc);
                    h_bf[orow + h] = f2bf(hh);
                    h_out[orow + h] = hh;
                }
            }
        }
    }
}

extern "C" void kernel_launch(void* const* d_in, const int* in_sizes, int n_in,
                              void* d_out, int out_size, void* d_ws, size_t ws_size,
                              hipStream_t stream) {
    const float* emb  = (const float*)d_in[0];  // (B,N,IN) fp32
    const int*   conn = (const int*)d_in[1];    // (B,N) int32
    // d_in[2] node_mask: all ones, unused
    const float* wl   = (const float*)d_in[3];  // (3,8,64,512) fp32
    const float* wr   = (const float*)d_in[4];  // (3,8,64,512) fp32
    const float* wo   = (const float*)d_in[5];  // (3,512,8)    fp32
    const float* ul   = (const float*)d_in[6];  // (3,512,512)  fp32
    const float* ur   = (const float*)d_in[7];  // (3,512,512)  fp32
    const float* bias = (const float*)d_in[8];  // (3,512)      fp32

    char* ws = (char*)d_ws;
    int* offs   = (int*)ws;          // 520
    int* counts = offs + 520;        // 520
    int* cursor = counts + 520;      // 520
    unsigned char* lvl_g = (unsigned char*)(ws + 8192);   // 64 KiB
    u32* list = (u32*)(ws + 8192 + 65536);                // 256 KiB
    // bf16 staging (byte offsets from ws base):
    short* wlb = (short*)(ws + 335872);                   // 786432 el
    short* wrb = wlb + 786432;
    short* ulb = wrb + 786432;
    short* urb = ulb + 786432;                            // ends ~6.6 MB
    short* embb = (short*)(ws + (8u << 20));              // 64 MiB
    short* h_bf = (short*)(ws + (8u << 20) + 67108864u);
    short* c_bf = (short*)(ws + (8u << 20) + 134217728u); // ends at 200 MiB
    float* pooled2 = (float*)(ws + 209715200ull);         // 6.3 MB (needs ws >= 216 MiB)

    float* h_out = (float*)d_out;

    // fp32 -> bf16 staging
    conv_kernel<<<dim3(2048), dim3(256), 0, stream>>>(emb, embb, NODES * 512 / 4);
    conv_kernel<<<dim3(256), dim3(256), 0, stream>>>(wl, wlb, 786432 / 4);
    conv_kernel<<<dim3(256), dim3(256), 0, stream>>>(wr, wrb, 786432 / 4);
    conv_kernel<<<dim3(256), dim3(256), 0, stream>>>(ul, ulb, 786432 / 4);
    conv_kernel<<<dim3(256), dim3(256), 0, stream>>>(ur, urb, 786432 / 4);

    // parallel setup: zero -> depth(pointer doubling)+hist -> scan -> scatter
    zero_kernel<<<dim3(3), dim3(256), 0, stream>>>(counts);
    depth_kernel<<<dim3(NB), dim3(256), 0, stream>>>(conn, lvl_g, counts);
    scan_kernel<<<dim3(1), dim3(256), 0, stream>>>(counts, offs, cursor);
    scatter_kernel<<<dim3(NB), dim3(256), 0, stream>>>(conn, lvl_g, cursor, list);

    for (int l = 0; l < NLEVELS; l++) {
        if (l > 0)
            pool_kernel<<<dim3(480), dim3(256), 0, stream>>>(
                l, embb, wlb, wrb, h_bf, offs, list, pooled2);
        gemm_lin_kernel<<<dim3(512), dim3(256), 0, stream>>>(
            l, embb, ulb, urb, wo, bias, offs, list, pooled2, h_out, h_bf, c_bf);
    }
}